// Round 1
// baseline (4069.661 us; speedup 1.0000x reference)
//
#include <hip/hip_runtime.h>
#include <math.h>

#define T_SEQ 2048
#define D_MODEL 1024
#define NHEAD 16
#define DHEAD 64
#define FF_DIM 4096
#define NTOK 4096   // B*T
#define LN_EPS 1e-6f

// ---------------------------------------------------------------------------
// Generic fp32 GEMM: C[m,n] = scale * sum_k A[m,k]*B(k,n)  (+bias) (relu)
// BLAY=0: B is [K,N] row-major.  BLAY=1: B is [N,K] row-major (B^T GEMM).
// Tiles: BM=BN=64, BK=16. 256 threads, 4x4 per-thread microtile.
// M,N,K must be multiples of 64/64/16 (true for all calls here).
// ---------------------------------------------------------------------------
template <int BLAY, bool BIAS, bool RELU>
__global__ __launch_bounds__(256) void gemm_f32(
    const float* __restrict__ A, const float* __restrict__ B,
    const float* __restrict__ bias, float* __restrict__ C,
    int M, int N, int K, float scale) {
  __shared__ float As[16][64];  // As[k][m]
  __shared__ float Bs[16][64];  // Bs[k][n]

  const int tid = threadIdx.x;
  const int ty = tid >> 4;   // 0..15  -> row group
  const int tx = tid & 15;   // 0..15  -> col group
  const int m0 = blockIdx.y * 64;
  const int n0 = blockIdx.x * 64;

  float acc[4][4] = {};

  for (int k0 = 0; k0 < K; k0 += 16) {
    // ---- load A tile 64x16 -> As[k][m], float4 along k
    {
      const int m = tid >> 2;             // 0..63
      const int kq = (tid & 3) * 4;       // 0,4,8,12
      const float4 a4 =
          *(const float4*)&A[(size_t)(m0 + m) * K + k0 + kq];
      As[kq + 0][m] = a4.x;
      As[kq + 1][m] = a4.y;
      As[kq + 2][m] = a4.z;
      As[kq + 3][m] = a4.w;
    }
    // ---- load B tile -> Bs[k][n]
    if (BLAY == 0) {
      const int k = tid >> 4;            // 0..15
      const int n = (tid & 15) * 4;      // 0..60
      const float4 b4 =
          *(const float4*)&B[(size_t)(k0 + k) * N + n0 + n];
      *(float4*)&Bs[k][n] = b4;
    } else {
      const int n = tid >> 2;            // 0..63
      const int kq = (tid & 3) * 4;      // 0,4,8,12
      const float4 b4 =
          *(const float4*)&B[(size_t)(n0 + n) * K + k0 + kq];
      Bs[kq + 0][n] = b4.x;
      Bs[kq + 1][n] = b4.y;
      Bs[kq + 2][n] = b4.z;
      Bs[kq + 3][n] = b4.w;
    }
    __syncthreads();

#pragma unroll
    for (int kk = 0; kk < 16; ++kk) {
      const float4 a4 = *(const float4*)&As[kk][ty * 4];
      const float4 b4 = *(const float4*)&Bs[kk][tx * 4];
      const float a_[4] = {a4.x, a4.y, a4.z, a4.w};
      const float b_[4] = {b4.x, b4.y, b4.z, b4.w};
#pragma unroll
      for (int i = 0; i < 4; ++i)
#pragma unroll
        for (int j = 0; j < 4; ++j) acc[i][j] = fmaf(a_[i], b_[j], acc[i][j]);
    }
    __syncthreads();
  }

  // ---- epilogue
  float4 bia = make_float4(0.f, 0.f, 0.f, 0.f);
  if (BIAS) bia = *(const float4*)&bias[n0 + tx * 4];
#pragma unroll
  for (int i = 0; i < 4; ++i) {
    float4 o4;
    o4.x = acc[i][0] * scale;
    o4.y = acc[i][1] * scale;
    o4.z = acc[i][2] * scale;
    o4.w = acc[i][3] * scale;
    if (BIAS) {
      o4.x += bia.x; o4.y += bia.y; o4.z += bia.z; o4.w += bia.w;
    }
    if (RELU) {
      o4.x = fmaxf(o4.x, 0.f); o4.y = fmaxf(o4.y, 0.f);
      o4.z = fmaxf(o4.z, 0.f); o4.w = fmaxf(o4.w, 0.f);
    }
    *(float4*)&C[(size_t)(m0 + ty * 4 + i) * N + n0 + tx * 4] = o4;
  }
}

// ---------------------------------------------------------------------------
// Causal flash attention. q,k,v,ctx layout: [B, T, H, 64] fp32.
// Grid: (T/64, B*H). Block: 64 threads, thread = one q row.
// q is pre-scaled by 1/sqrt(DK) in the q GEMM.
// ---------------------------------------------------------------------------
__global__ __launch_bounds__(64) void attn_flash(
    const float* __restrict__ q, const float* __restrict__ k,
    const float* __restrict__ v, float* __restrict__ ctx) {
  __shared__ float Ks[64][64];
  __shared__ float Vs[64][64];

  const int tid = threadIdx.x;
  const int bh = blockIdx.y;
  const int b = bh >> 4;
  const int h = bh & 15;
  const int t = blockIdx.x * 64 + tid;  // this thread's q row (global)

  const float* qrow = q + ((size_t)(b * T_SEQ + t) * NHEAD + h) * DHEAD;
  alignas(16) float qr[64];
#pragma unroll
  for (int i = 0; i < 16; ++i) ((float4*)qr)[i] = ((const float4*)qrow)[i];

  alignas(16) float o[64];
#pragma unroll
  for (int i = 0; i < 64; ++i) o[i] = 0.f;
  float m = -INFINITY, l = 0.f;

  const int send = blockIdx.x * 64 + 63;  // last needed key row
  for (int s0 = 0; s0 <= send; s0 += 64) {
    // stage K,V tiles (64x64), float4-coalesced
#pragma unroll
    for (int rep = 0; rep < 16; ++rep) {
      const int r = rep * 4 + (tid >> 4);
      const int dd = (tid & 15) * 4;
      const size_t g = ((size_t)(b * T_SEQ + s0 + r) * NHEAD + h) * DHEAD + dd;
      *(float4*)&Ks[r][dd] = *(const float4*)&k[g];
      *(float4*)&Vs[r][dd] = *(const float4*)&v[g];
    }
    __syncthreads();

    const int cmax = min(63, t - s0);  // negative -> skip (fully masked)
    for (int c = 0; c <= cmax; ++c) {
      float sc = 0.f;
      const float4* kr = (const float4*)Ks[c];
#pragma unroll
      for (int d4 = 0; d4 < 16; ++d4) {
        const float4 kk4 = kr[d4];  // broadcast (same addr all lanes)
        sc = fmaf(qr[d4 * 4 + 0], kk4.x, sc);
        sc = fmaf(qr[d4 * 4 + 1], kk4.y, sc);
        sc = fmaf(qr[d4 * 4 + 2], kk4.z, sc);
        sc = fmaf(qr[d4 * 4 + 3], kk4.w, sc);
      }
      const float mn = fmaxf(m, sc);
      const float corr = __expf(m - mn);
      const float p = __expf(sc - mn);
      l = l * corr + p;
      const float4* vr = (const float4*)Vs[c];
#pragma unroll
      for (int d4 = 0; d4 < 16; ++d4) {
        const float4 vv4 = vr[d4];
        o[d4 * 4 + 0] = fmaf(o[d4 * 4 + 0], corr, p * vv4.x);
        o[d4 * 4 + 1] = fmaf(o[d4 * 4 + 1], corr, p * vv4.y);
        o[d4 * 4 + 2] = fmaf(o[d4 * 4 + 2], corr, p * vv4.z);
        o[d4 * 4 + 3] = fmaf(o[d4 * 4 + 3], corr, p * vv4.w);
      }
      m = mn;
    }
    __syncthreads();
  }

  const float inv = 1.0f / l;
  float* crow = ctx + ((size_t)(b * T_SEQ + t) * NHEAD + h) * DHEAD;
#pragma unroll
  for (int i = 0; i < 16; ++i) {
    float4 o4;
    o4.x = o[i * 4 + 0] * inv;
    o4.y = o[i * 4 + 1] * inv;
    o4.z = o[i * 4 + 2] * inv;
    o4.w = o[i * 4 + 3] * inv;
    ((float4*)crow)[i] = o4;
  }
}

// ---------------------------------------------------------------------------
// out = LayerNorm(x + y) * g + be   over last dim (1024). One block per row.
// ---------------------------------------------------------------------------
__global__ __launch_bounds__(256) void add_layernorm(
    const float* __restrict__ x, const float* __restrict__ y,
    const float* __restrict__ g, const float* __restrict__ be,
    float* __restrict__ out) {
  const int row = blockIdx.x;
  const int tid = threadIdx.x;
  const size_t base = (size_t)row * D_MODEL + tid * 4;

  const float4 xv = *(const float4*)&x[base];
  const float4 yv = *(const float4*)&y[base];
  const float v0 = xv.x + yv.x, v1 = xv.y + yv.y;
  const float v2 = xv.z + yv.z, v3 = xv.w + yv.w;

  float s = v0 + v1 + v2 + v3;
  float ss = v0 * v0 + v1 * v1 + v2 * v2 + v3 * v3;
#pragma unroll
  for (int off = 32; off > 0; off >>= 1) {
    s += __shfl_down(s, off);
    ss += __shfl_down(ss, off);
  }
  __shared__ float red[8];
  const int wid = tid >> 6, lane = tid & 63;
  if (lane == 0) { red[wid] = s; red[4 + wid] = ss; }
  __syncthreads();
  s = red[0] + red[1] + red[2] + red[3];
  ss = red[4] + red[5] + red[6] + red[7];

  const float mean = s * (1.0f / D_MODEL);
  const float var = ss * (1.0f / D_MODEL) - mean * mean;
  const float r = rsqrtf(var + LN_EPS);

  const float4 g4 = *(const float4*)&g[tid * 4];
  const float4 b4 = *(const float4*)&be[tid * 4];
  float4 o4;
  o4.x = (v0 - mean) * r * g4.x + b4.x;
  o4.y = (v1 - mean) * r * g4.y + b4.y;
  o4.z = (v2 - mean) * r * g4.z + b4.z;
  o4.w = (v3 - mean) * r * g4.w + b4.w;
  *(float4*)&out[base] = o4;
}

// ---------------------------------------------------------------------------
extern "C" void kernel_launch(void* const* d_in, const int* in_sizes, int n_in,
                              void* d_out, int out_size, void* d_ws,
                              size_t ws_size, hipStream_t stream) {
  const float* x  = (const float*)d_in[0];   // [B,T,D]
  const float* Wq = (const float*)d_in[1];   // [D, H*DK] = [1024,1024]
  const float* Wk = (const float*)d_in[2];
  const float* Wv = (const float*)d_in[3];
  const float* Wo = (const float*)d_in[4];   // [D, H*DV]  (used transposed)
  const float* W1 = (const float*)d_in[5];   // [1024,4096]
  const float* b1 = (const float*)d_in[6];
  const float* W2 = (const float*)d_in[7];   // [4096,1024]
  const float* b2 = (const float*)d_in[8];
  const float* g1 = (const float*)d_in[9];
  const float* be1 = (const float*)d_in[10];
  const float* g2 = (const float*)d_in[11];
  const float* be2 = (const float*)d_in[12];

  float* ws = (float*)d_ws;
  const size_t R = (size_t)1 << 22;  // 4M floats = 16 MB per region
  float* q    = ws + 0 * R;
  float* k    = ws + 1 * R;
  float* v    = ws + 2 * R;
  float* ctx  = ws + 3 * R;
  float* attn = ws + 0 * R;  // reuse q (dead after attention)
  float* h    = ws + 4 * R;
  float* ffn1 = ws + 0 * R;  // reuse q/k/v/ctx (16M floats)
  float* ffn2 = ws + 5 * R;

  const dim3 blk(256);
  const dim3 g1024(D_MODEL / 64, NTOK / 64);   // (16, 64)
  const dim3 gff1(FF_DIM / 64, NTOK / 64);     // (64, 64)

  const float qscale = 0.125f;  // 1/sqrt(64)

  gemm_f32<0, false, false><<<g1024, blk, 0, stream>>>(
      x, Wq, nullptr, q, NTOK, D_MODEL, D_MODEL, qscale);
  gemm_f32<0, false, false><<<g1024, blk, 0, stream>>>(
      x, Wk, nullptr, k, NTOK, D_MODEL, D_MODEL, 1.f);
  gemm_f32<0, false, false><<<g1024, blk, 0, stream>>>(
      x, Wv, nullptr, v, NTOK, D_MODEL, D_MODEL, 1.f);

  attn_flash<<<dim3(T_SEQ / 64, 32), dim3(64), 0, stream>>>(q, k, v, ctx);

  gemm_f32<1, false, false><<<g1024, blk, 0, stream>>>(
      ctx, Wo, nullptr, attn, NTOK, D_MODEL, D_MODEL, 1.f);

  add_layernorm<<<NTOK, blk, 0, stream>>>(x, attn, g1, be1, h);

  gemm_f32<0, true, true><<<gff1, blk, 0, stream>>>(
      h, W1, b1, ffn1, NTOK, FF_DIM, D_MODEL, 1.f);
  gemm_f32<0, true, false><<<g1024, blk, 0, stream>>>(
      ffn1, W2, b2, ffn2, NTOK, D_MODEL, FF_DIM, 1.f);

  add_layernorm<<<NTOK, blk, 0, stream>>>(h, ffn2, g2, be2, (float*)d_out);
}

// Round 2
// 1465.106 us; speedup vs baseline: 2.7777x; 2.7777x over previous
//
#include <hip/hip_runtime.h>
#include <math.h>

#define T_SEQ 2048
#define D_MODEL 1024
#define NHEAD 16
#define DHEAD 64
#define FF_DIM 4096
#define NTOK 4096   // B*T
#define LN_EPS 1e-6f

typedef unsigned short u16;
typedef __attribute__((ext_vector_type(8))) __bf16 bf16x8;
typedef __attribute__((ext_vector_type(4))) float f32x4;

typedef const void __attribute__((address_space(1))) gvoid;
typedef void __attribute__((address_space(3))) lvoid;

__device__ __forceinline__ u16 f2bf(float f) {
  unsigned u = __float_as_uint(f);
  return (u16)((u + 0x7fffu + ((u >> 16) & 1u)) >> 16);
}

// async global(16B/lane) -> LDS, wave-linear dest: lane l lands at l*16 bytes
__device__ __forceinline__ void gll16(const u16* g, u16* l) {
  __builtin_amdgcn_global_load_lds((gvoid*)g, (lvoid*)l, 16, 0, 0);
}

// ---------------------------------------------------------------------------
// fp32 -> bf16 flat convert (n % 1024 == 0)
// ---------------------------------------------------------------------------
__global__ __launch_bounds__(256) void conv_f2b(const float* __restrict__ in,
                                                u16* __restrict__ out, int n) {
  const int i = (blockIdx.x * 256 + threadIdx.x) * 4;
  if (i >= n) return;
  const float4 v = *(const float4*)&in[i];
  ushort4 o;
  o.x = f2bf(v.x); o.y = f2bf(v.y); o.z = f2bf(v.z); o.w = f2bf(v.w);
  *(ushort4*)&out[i] = o;
}

// ---------------------------------------------------------------------------
// fp32 [K,N] -> bf16 [N,K] transpose. 64x64 tiles. grid (N/64, K/64)
// ---------------------------------------------------------------------------
__global__ __launch_bounds__(256) void transpose_f2b(
    const float* __restrict__ in, u16* __restrict__ out, int K, int N) {
  __shared__ u16 t[64][72];  // 72: keeps 16B alignment of rows, breaks pow2
  const int tid = threadIdx.x;
  const int k0 = blockIdx.y * 64, n0 = blockIdx.x * 64;
  const int nl = tid & 63;
#pragma unroll
  for (int i = 0; i < 16; ++i) {
    const int kl = (tid >> 6) * 16 + i;
    t[nl][kl] = f2bf(in[(size_t)(k0 + kl) * N + n0 + nl]);
  }
  __syncthreads();
  const int nr = tid >> 2, kc = (tid & 3) * 16;
  const uint4 a = *(const uint4*)&t[nr][kc];
  const uint4 b = *(const uint4*)&t[nr][kc + 8];
  *(uint4*)&out[(size_t)(n0 + nr) * K + k0 + kc] = a;
  *(uint4*)&out[(size_t)(n0 + nr) * K + k0 + kc + 8] = b;
}

// ---------------------------------------------------------------------------
// bf16 MFMA GEMM (m97 structure). C[m,n] = scale*sum_k A[m,k]*BT[n,k] (+bias)
// A: [M,K] bf16, BT: [N,K] bf16. 128x128 tile, BK=32, 256 thr (4 waves).
// Wave w owns 64x64 at (w>>1, w&1). acc 4x4 of 16x16 mfma tiles.
// M%128==0, N%128==0, K%32==0.
// ---------------------------------------------------------------------------
template <bool BIAS, bool RELU, bool OUT_BF16>
__global__ __launch_bounds__(256) void gemm_mfma(
    const u16* __restrict__ A, const u16* __restrict__ BT,
    const float* __restrict__ bias, void* __restrict__ C,
    int M, int N, int K, float scale) {
  __shared__ u16 Al[128 * 32];
  __shared__ u16 Bl[128 * 32];
  const int tid = threadIdx.x;
  const int w = tid >> 6, lane = tid & 63;
  const int m0 = blockIdx.y * 128, n0 = blockIdx.x * 128;
  const int wr = (w >> 1) * 64, wc = (w & 1) * 64;

  f32x4 acc[4][4];
#pragma unroll
  for (int i = 0; i < 4; ++i)
#pragma unroll
    for (int j = 0; j < 4; ++j) acc[i][j] = (f32x4)0.f;

  // staging: instruction i = w*2+s covers rows [i*16, i*16+16)
  const int srow = w * 32 + (lane >> 2);   // + {0,16} for s=0,1
  const int scol = (lane & 3) * 8;
  const u16* gA0 = A + (size_t)(m0 + srow) * K + scol;
  const u16* gA1 = gA0 + (size_t)16 * K;
  const u16* gB0 = BT + (size_t)(n0 + srow) * K + scol;
  const u16* gB1 = gB0 + (size_t)16 * K;
  u16* lA0 = &Al[(w * 32) * 32];
  u16* lA1 = &Al[(w * 32 + 16) * 32];
  u16* lB0 = &Bl[(w * 32) * 32];
  u16* lB1 = &Bl[(w * 32 + 16) * 32];

  const int arow = lane & 15;        // fragment row/col within 16
  const int koff = (lane >> 4) * 8;  // fragment k slice

  for (int k0 = 0; k0 < K; k0 += 32) {
    gll16(gA0 + k0, lA0);
    gll16(gA1 + k0, lA1);
    gll16(gB0 + k0, lB0);
    gll16(gB1 + k0, lB1);
    __syncthreads();  // drains vmcnt -> LDS tiles ready

    bf16x8 af[4], bff[4];
#pragma unroll
    for (int m = 0; m < 4; ++m)
      af[m] = *(const bf16x8*)&Al[(wr + m * 16 + arow) * 32 + koff];
#pragma unroll
    for (int n = 0; n < 4; ++n)
      bff[n] = *(const bf16x8*)&Bl[(wc + n * 16 + arow) * 32 + koff];
#pragma unroll
    for (int m = 0; m < 4; ++m)
#pragma unroll
      for (int n = 0; n < 4; ++n)
        acc[m][n] = __builtin_amdgcn_mfma_f32_16x16x32_bf16(
            af[m], bff[n], acc[m][n], 0, 0, 0);
    __syncthreads();  // compute done before next stage overwrites LDS
  }

  // epilogue: D layout col=lane&15, row=(lane>>4)*4+reg  [m89-verified]
  const int rbase = (lane >> 4) * 4;
  const int cl = lane & 15;
#pragma unroll
  for (int n = 0; n < 4; ++n) {
    const int col = n0 + wc + n * 16 + cl;
    const float bia = BIAS ? bias[col] : 0.f;
#pragma unroll
    for (int m = 0; m < 4; ++m) {
      const int row0 = m0 + wr + m * 16 + rbase;
#pragma unroll
      for (int r = 0; r < 4; ++r) {
        float vv = acc[m][n][r] * scale + bia;
        if (RELU) vv = fmaxf(vv, 0.f);
        if (OUT_BF16)
          ((u16*)C)[(size_t)(row0 + r) * N + col] = f2bf(vv);
        else
          ((float*)C)[(size_t)(row0 + r) * N + col] = vv;
      }
    }
  }
}

// ---------------------------------------------------------------------------
// Causal flash attention, fp32, parallel. q,k,v: [B,T,H,64] fp32.
// Block: 256 thr (4 waves). Wave handles 16 q rows; lane = part*16 + r:
// r = q-row within wave band, part = 16-dim slice. Output ctx in bf16.
// Grid: (T/64, B*H).
// ---------------------------------------------------------------------------
__global__ __launch_bounds__(256) void attn_flash2(
    const float* __restrict__ q, const float* __restrict__ k,
    const float* __restrict__ v, u16* __restrict__ ctx_bf) {
  __shared__ float Ks[64][64];
  __shared__ float Vs[64][64];
  const int tid = threadIdx.x;
  const int wave = tid >> 6, lane = tid & 63;
  const int r = lane & 15, part = lane >> 4;
  const int bh = blockIdx.y, b = bh >> 4, h = bh & 15;
  const int t = blockIdx.x * 64 + wave * 16 + r;

  const float* qrow =
      q + ((size_t)(b * T_SEQ + t) * NHEAD + h) * DHEAD + part * 16;
  float4 q0 = ((const float4*)qrow)[0];
  float4 q1 = ((const float4*)qrow)[1];
  float4 q2 = ((const float4*)qrow)[2];
  float4 q3 = ((const float4*)qrow)[3];

  float o[16];
#pragma unroll
  for (int j = 0; j < 16; ++j) o[j] = 0.f;
  float m = -INFINITY, l = 0.f;

  const int send = blockIdx.x * 64 + 63;
  for (int s0 = 0; s0 <= send; s0 += 64) {
    // stage K,V 64x64 (256 threads, 4 rows each, float4)
#pragma unroll
    for (int rep = 0; rep < 4; ++rep) {
      const int rr = rep * 16 + (tid >> 4);
      const int dd = (tid & 15) * 4;
      const size_t g =
          ((size_t)(b * T_SEQ + s0 + rr) * NHEAD + h) * DHEAD + dd;
      *(float4*)&Ks[rr][dd] = *(const float4*)&k[g];
      *(float4*)&Vs[rr][dd] = *(const float4*)&v[g];
    }
    __syncthreads();

    const int cmax = min(63, t - s0);
    for (int c = 0; c <= cmax; ++c) {
      const float4* kr = (const float4*)&Ks[c][part * 16];
      const float4 k0v = kr[0], k1v = kr[1], k2v = kr[2], k3v = kr[3];
      float d0 = q0.x * k0v.x + q0.y * k0v.y + q0.z * k0v.z + q0.w * k0v.w;
      float d1 = q1.x * k1v.x + q1.y * k1v.y + q1.z * k1v.z + q1.w * k1v.w;
      float d2 = q2.x * k2v.x + q2.y * k2v.y + q2.z * k2v.z + q2.w * k2v.w;
      float d3 = q3.x * k3v.x + q3.y * k3v.y + q3.z * k3v.z + q3.w * k3v.w;
      float sc = (d0 + d1) + (d2 + d3);
      sc += __shfl_xor(sc, 16);
      sc += __shfl_xor(sc, 32);
      const float mn = fmaxf(m, sc);
      const float corr = __expf(m - mn);
      const float p = __expf(sc - mn);
      l = l * corr + p;
      m = mn;
      const float* vr = &Vs[c][part * 16];
#pragma unroll
      for (int j = 0; j < 16; ++j) o[j] = o[j] * corr + p * vr[j];
    }
    __syncthreads();
  }

  const float inv = 1.0f / l;
  alignas(16) u16 tmp[16];
#pragma unroll
  for (int j = 0; j < 16; ++j) tmp[j] = f2bf(o[j] * inv);
  u16* dst = ctx_bf + ((size_t)(b * T_SEQ + t) * NHEAD + h) * DHEAD + part * 16;
  ((uint4*)dst)[0] = *(const uint4*)&tmp[0];
  ((uint4*)dst)[1] = *(const uint4*)&tmp[8];
}

// ---------------------------------------------------------------------------
// out = LayerNorm(x + y) * g + be  over last dim 1024. Optional bf16 copy.
// ---------------------------------------------------------------------------
template <bool EMIT_BF>
__global__ __launch_bounds__(256) void add_layernorm(
    const float* __restrict__ x, const float* __restrict__ y,
    const float* __restrict__ g, const float* __restrict__ be,
    float* __restrict__ out, u16* __restrict__ out_bf) {
  const int row = blockIdx.x;
  const int tid = threadIdx.x;
  const size_t base = (size_t)row * D_MODEL + tid * 4;

  const float4 xv = *(const float4*)&x[base];
  const float4 yv = *(const float4*)&y[base];
  const float v0 = xv.x + yv.x, v1 = xv.y + yv.y;
  const float v2 = xv.z + yv.z, v3 = xv.w + yv.w;

  float s = v0 + v1 + v2 + v3;
  float ss = v0 * v0 + v1 * v1 + v2 * v2 + v3 * v3;
#pragma unroll
  for (int off = 32; off > 0; off >>= 1) {
    s += __shfl_down(s, off);
    ss += __shfl_down(ss, off);
  }
  __shared__ float red[8];
  const int wid = tid >> 6, lane = tid & 63;
  if (lane == 0) { red[wid] = s; red[4 + wid] = ss; }
  __syncthreads();
  s = red[0] + red[1] + red[2] + red[3];
  ss = red[4] + red[5] + red[6] + red[7];

  const float mean = s * (1.0f / D_MODEL);
  const float var = ss * (1.0f / D_MODEL) - mean * mean;
  const float rr = rsqrtf(var + LN_EPS);

  const float4 g4 = *(const float4*)&g[tid * 4];
  const float4 b4 = *(const float4*)&be[tid * 4];
  float4 o4;
  o4.x = (v0 - mean) * rr * g4.x + b4.x;
  o4.y = (v1 - mean) * rr * g4.y + b4.y;
  o4.z = (v2 - mean) * rr * g4.z + b4.z;
  o4.w = (v3 - mean) * rr * g4.w + b4.w;
  *(float4*)&out[base] = o4;
  if (EMIT_BF) {
    ushort4 ob;
    ob.x = f2bf(o4.x); ob.y = f2bf(o4.y); ob.z = f2bf(o4.z); ob.w = f2bf(o4.w);
    *(ushort4*)&out_bf[base] = ob;
  }
}

// ---------------------------------------------------------------------------
extern "C" void kernel_launch(void* const* d_in, const int* in_sizes, int n_in,
                              void* d_out, int out_size, void* d_ws,
                              size_t ws_size, hipStream_t stream) {
  const float* x  = (const float*)d_in[0];
  const float* Wq = (const float*)d_in[1];
  const float* Wk = (const float*)d_in[2];
  const float* Wv = (const float*)d_in[3];
  const float* Wo = (const float*)d_in[4];
  const float* W1 = (const float*)d_in[5];
  const float* b1 = (const float*)d_in[6];
  const float* W2 = (const float*)d_in[7];
  const float* b2 = (const float*)d_in[8];
  const float* g1 = (const float*)d_in[9];
  const float* be1 = (const float*)d_in[10];
  const float* g2 = (const float*)d_in[11];
  const float* be2 = (const float*)d_in[12];

  char* ws = (char*)d_ws;
  const size_t MB = 1u << 20;
  u16*   x_bf    = (u16*)(ws + 0 * MB);     // 8MB   [4096,1024]
  u16*   WqT     = (u16*)(ws + 8 * MB);     // 2MB   [1024,1024] (n,k)
  u16*   WkT     = (u16*)(ws + 10 * MB);    // 2MB
  u16*   WvT     = (u16*)(ws + 12 * MB);    // 2MB
  u16*   WoB     = (u16*)(ws + 14 * MB);    // 2MB   [1024,1024] (already n,k)
  u16*   W1T     = (u16*)(ws + 16 * MB);    // 8MB   [4096,1024]
  u16*   W2T     = (u16*)(ws + 24 * MB);    // 8MB   [1024,4096]
  float* q       = (float*)(ws + 32 * MB);  // 16MB  [4096,16,64]
  float* k       = (float*)(ws + 48 * MB);  // 16MB
  float* v       = (float*)(ws + 64 * MB);  // 16MB
  u16*   ctx_bf  = (u16*)(ws + 80 * MB);    // 8MB
  float* attn    = (float*)(ws + 32 * MB);  // reuse q (dead after attn)
  float* h       = (float*)(ws + 64 * MB);  // reuse v (dead after attn)
  u16*   h_bf    = (u16*)(ws + 80 * MB);    // reuse ctx_bf (dead after WoGEMM)
  u16*   ffn1_bf = (u16*)(ws + 32 * MB);    // 32MB, reuse attn+k regions
  float* ffn2    = (float*)(ws + 0 * MB);   // 16MB, reuse x_bf+W[qkvo] regions

  const dim3 blk(256);

  // ---- convert / transpose weights & activations to bf16
  conv_f2b<<<NTOK * D_MODEL / 1024, blk, 0, stream>>>(x, x_bf, NTOK * D_MODEL);
  transpose_f2b<<<dim3(16, 16), blk, 0, stream>>>(Wq, WqT, D_MODEL, D_MODEL);
  transpose_f2b<<<dim3(16, 16), blk, 0, stream>>>(Wk, WkT, D_MODEL, D_MODEL);
  transpose_f2b<<<dim3(16, 16), blk, 0, stream>>>(Wv, WvT, D_MODEL, D_MODEL);
  conv_f2b<<<D_MODEL * D_MODEL / 1024, blk, 0, stream>>>(Wo, WoB,
                                                         D_MODEL * D_MODEL);
  transpose_f2b<<<dim3(64, 16), blk, 0, stream>>>(W1, W1T, D_MODEL, FF_DIM);
  transpose_f2b<<<dim3(16, 64), blk, 0, stream>>>(W2, W2T, FF_DIM, D_MODEL);

  // ---- QKV projections (q pre-scaled by 1/sqrt(dk))
  const dim3 g1024(D_MODEL / 128, NTOK / 128);  // (8,32)
  const dim3 gff(FF_DIM / 128, NTOK / 128);     // (32,32)
  gemm_mfma<false, false, false><<<g1024, blk, 0, stream>>>(
      x_bf, WqT, nullptr, q, NTOK, D_MODEL, D_MODEL, 0.125f);
  gemm_mfma<false, false, false><<<g1024, blk, 0, stream>>>(
      x_bf, WkT, nullptr, k, NTOK, D_MODEL, D_MODEL, 1.f);
  gemm_mfma<false, false, false><<<g1024, blk, 0, stream>>>(
      x_bf, WvT, nullptr, v, NTOK, D_MODEL, D_MODEL, 1.f);

  // ---- attention
  attn_flash2<<<dim3(T_SEQ / 64, 32), blk, 0, stream>>>(q, k, v, ctx_bf);

  // ---- output projection
  gemm_mfma<false, false, false><<<g1024, blk, 0, stream>>>(
      ctx_bf, WoB, nullptr, attn, NTOK, D_MODEL, D_MODEL, 1.f);

  // ---- LN1 (emit fp32 h + bf16 h_bf)
  add_layernorm<true><<<NTOK, blk, 0, stream>>>(x, attn, g1, be1, h, h_bf);

  // ---- FFN
  gemm_mfma<true, true, true><<<gff, blk, 0, stream>>>(
      h_bf, W1T, b1, ffn1_bf, NTOK, FF_DIM, D_MODEL, 1.f);
  gemm_mfma<true, false, false><<<g1024, blk, 0, stream>>>(
      ffn1_bf, W2T, b2, ffn2, NTOK, D_MODEL, FF_DIM, 1.f);

  // ---- LN2 -> output
  add_layernorm<false><<<NTOK, blk, 0, stream>>>(h, ffn2, g2, be2,
                                                 (float*)d_out, nullptr);
}

// Round 3
// 530.705 us; speedup vs baseline: 7.6684x; 2.7607x over previous
//
#include <hip/hip_runtime.h>
#include <math.h>

#define T_SEQ 2048
#define D_MODEL 1024
#define NHEAD 16
#define DHEAD 64
#define FF_DIM 4096
#define NTOK 4096   // B*T
#define LN_EPS 1e-6f

typedef unsigned short u16;
typedef __attribute__((ext_vector_type(8))) __bf16 bf16x8;
typedef __attribute__((ext_vector_type(4))) float f32x4;

typedef const void __attribute__((address_space(1))) gvoid;
typedef void __attribute__((address_space(3))) lvoid;

__device__ __forceinline__ u16 f2bf(float f) {
  unsigned u = __float_as_uint(f);
  return (u16)((u + 0x7fffu + ((u >> 16) & 1u)) >> 16);
}

// async global(16B/lane) -> LDS; dest = wave-uniform base + lane*16B
__device__ __forceinline__ void gll16(const u16* g, u16* l) {
  __builtin_amdgcn_global_load_lds((gvoid*)g, (lvoid*)l, 16, 0, 0);
}

// read one 16B fragment from a [rows][64] bf16 LDS tile with chunk-XOR swizzle
__device__ __forceinline__ bf16x8 lds_frag(const u16* lds, int row, int chunk) {
  return *(const bf16x8*)&lds[row * 64 + ((chunk ^ (row & 7)) * 8)];
}

// ---------------------------------------------------------------------------
// fp32 -> bf16 flat convert (n % 1024 == 0)
// ---------------------------------------------------------------------------
__global__ __launch_bounds__(256) void conv_f2b(const float* __restrict__ in,
                                                u16* __restrict__ out, int n) {
  const int i = (blockIdx.x * 256 + threadIdx.x) * 4;
  if (i >= n) return;
  const float4 v = *(const float4*)&in[i];
  ushort4 o;
  o.x = f2bf(v.x); o.y = f2bf(v.y); o.z = f2bf(v.z); o.w = f2bf(v.w);
  *(ushort4*)&out[i] = o;
}

// ---------------------------------------------------------------------------
// fp32 [K,N] -> bf16 [N,K] transpose (optional scale). 64x64 tiles.
// ---------------------------------------------------------------------------
__global__ __launch_bounds__(256) void transpose_f2b(
    const float* __restrict__ in, u16* __restrict__ out, int K, int N,
    float scale) {
  __shared__ u16 t[64][72];
  const int tid = threadIdx.x;
  const int k0 = blockIdx.y * 64, n0 = blockIdx.x * 64;
  const int nl = tid & 63;
#pragma unroll
  for (int i = 0; i < 16; ++i) {
    const int kl = (tid >> 6) * 16 + i;
    t[nl][kl] = f2bf(in[(size_t)(k0 + kl) * N + n0 + nl] * scale);
  }
  __syncthreads();
  const int nr = tid >> 2, kc = (tid & 3) * 16;
  const uint4 a = *(const uint4*)&t[nr][kc];
  const uint4 b = *(const uint4*)&t[nr][kc + 8];
  *(uint4*)&out[(size_t)(n0 + nr) * K + k0 + kc] = a;
  *(uint4*)&out[(size_t)(n0 + nr) * K + k0 + kc + 8] = b;
}

// ---------------------------------------------------------------------------
// bf16 MFMA GEMM. C[m,n] = scale*sum_k A[m,k]*BT[n,k] (+bias)(relu)
// OUTMODE: 0 f32 [M,N] | 1 bf16 [M,N] | 2 bf16 [B,H,T,64] | 3 bf16 [B,H,64,T]
// ---------------------------------------------------------------------------
template <int OUTMODE, bool BIAS, bool RELU>
__global__ __launch_bounds__(256) void gemm_mfma(
    const u16* __restrict__ A, const u16* __restrict__ BT,
    const float* __restrict__ bias, void* __restrict__ C,
    int M, int N, int K, float scale) {
  __shared__ u16 Al[128 * 32];
  __shared__ u16 Bl[128 * 32];
  const int tid = threadIdx.x;
  const int w = tid >> 6, lane = tid & 63;
  const int m0 = blockIdx.y * 128, n0 = blockIdx.x * 128;
  const int wr = (w >> 1) * 64, wc = (w & 1) * 64;

  f32x4 acc[4][4];
#pragma unroll
  for (int i = 0; i < 4; ++i)
#pragma unroll
    for (int j = 0; j < 4; ++j) acc[i][j] = (f32x4)0.f;

  const int srow = w * 32 + (lane >> 2);
  const int scol = (lane & 3) * 8;
  const u16* gA0 = A + (size_t)(m0 + srow) * K + scol;
  const u16* gA1 = gA0 + (size_t)16 * K;
  const u16* gB0 = BT + (size_t)(n0 + srow) * K + scol;
  const u16* gB1 = gB0 + (size_t)16 * K;
  u16* lA0 = &Al[(w * 32) * 32];
  u16* lA1 = &Al[(w * 32 + 16) * 32];
  u16* lB0 = &Bl[(w * 32) * 32];
  u16* lB1 = &Bl[(w * 32 + 16) * 32];

  const int arow = lane & 15;
  const int koff = (lane >> 4) * 8;

  for (int k0 = 0; k0 < K; k0 += 32) {
    gll16(gA0 + k0, lA0);
    gll16(gA1 + k0, lA1);
    gll16(gB0 + k0, lB0);
    gll16(gB1 + k0, lB1);
    __syncthreads();

    bf16x8 af[4], bff[4];
#pragma unroll
    for (int m = 0; m < 4; ++m)
      af[m] = *(const bf16x8*)&Al[(wr + m * 16 + arow) * 32 + koff];
#pragma unroll
    for (int n = 0; n < 4; ++n)
      bff[n] = *(const bf16x8*)&Bl[(wc + n * 16 + arow) * 32 + koff];
#pragma unroll
    for (int m = 0; m < 4; ++m)
#pragma unroll
      for (int n = 0; n < 4; ++n)
        acc[m][n] = __builtin_amdgcn_mfma_f32_16x16x32_bf16(
            af[m], bff[n], acc[m][n], 0, 0, 0);
    __syncthreads();
  }

  const int rbase = (lane >> 4) * 4;
  const int cl = lane & 15;
#pragma unroll
  for (int n = 0; n < 4; ++n) {
    const int col = n0 + wc + n * 16 + cl;
    const float bia = BIAS ? bias[col] : 0.f;
#pragma unroll
    for (int m = 0; m < 4; ++m) {
      const int row0 = m0 + wr + m * 16 + rbase;
#pragma unroll
      for (int r = 0; r < 4; ++r) {
        float vv = acc[m][n][r] * scale + bia;
        if (RELU) vv = fmaxf(vv, 0.f);
        const int row = row0 + r;
        if (OUTMODE == 0) {
          ((float*)C)[(size_t)row * N + col] = vv;
        } else if (OUTMODE == 1) {
          ((u16*)C)[(size_t)row * N + col] = f2bf(vv);
        } else if (OUTMODE == 2) {
          // [token][h*64+d] -> [B,H,T,64]
          const size_t off = ((size_t)(row >> 11) * NHEAD + (col >> 6)) *
                                 ((size_t)T_SEQ * 64) +
                             (size_t)(row & 2047) * 64 + (col & 63);
          ((u16*)C)[off] = f2bf(vv);
        } else {
          // [token][h*64+d] -> [B,H,64,T]
          const size_t off = ((size_t)(row >> 11) * NHEAD + (col >> 6)) *
                                 ((size_t)64 * T_SEQ) +
                             (size_t)(col & 63) * T_SEQ + (row & 2047);
          ((u16*)C)[off] = f2bf(vv);
        }
      }
    }
  }
}

// ---------------------------------------------------------------------------
// MFMA causal flash attention.
// q,k: [B,H,T,64] bf16. vT: [B,H,64,T] bf16. ctx out: [B,T,H,64] bf16.
// Grid: (T/64, B*H), 256 thr (4 waves). Wave w: q rows [qt*64+w*16, +16).
// ---------------------------------------------------------------------------
__global__ __launch_bounds__(256) void attn_mfma(
    const u16* __restrict__ qg, const u16* __restrict__ kg,
    const u16* __restrict__ vtg, u16* __restrict__ ctx) {
  __shared__ u16 Ks[2][64 * 64];
  __shared__ u16 Vs[2][64 * 64];
  __shared__ u16 Ps[4][16 * 64];

  const int tid = threadIdx.x;
  const int w = tid >> 6, lane = tid & 63;
  const int qt = gridDim.x - 1 - blockIdx.x;  // big blocks launch first
  const int bh = blockIdx.y;
  const int lo = lane & 15, hi = lane >> 4;
  const int r8 = lane >> 3, cswz = (lane & 7) ^ r8;

  const u16* qhead = qg + (size_t)bh * (T_SEQ * 64);
  const u16* khead = kg + (size_t)bh * (T_SEQ * 64);
  const u16* vhead = vtg + (size_t)bh * (64 * T_SEQ);

  // Q fragments, resident all kernel: A[row=lo][k=hi*8..] for 2 k-slices
  const int q0w = qt * 64 + w * 16;
  bf16x8 qa0 = *(const bf16x8*)&qhead[(size_t)(q0w + lo) * 64 + hi * 8];
  bf16x8 qa1 = *(const bf16x8*)&qhead[(size_t)(q0w + lo) * 64 + 32 + hi * 8];

  f32x4 o[4];
#pragma unroll
  for (int dt = 0; dt < 4; ++dt) o[dt] = (f32x4)0.f;
  float mrow[4] = {-INFINITY, -INFINITY, -INFINITY, -INFINITY};
  float lrow[4] = {0.f, 0.f, 0.f, 0.f};

  const int nt = qt + 1;

  // stage K tile rows (s) and V^T tile rows (d); wave w covers rows w*16..+15
  auto stage = [&](int buf, int s0) {
#pragma unroll
    for (int i = 0; i < 2; ++i) {
      const int row = w * 16 + i * 8 + r8;
      gll16(khead + (size_t)(s0 + row) * 64 + cswz * 8,
            &Ks[buf][(w * 16 + i * 8) * 64]);
      gll16(vhead + (size_t)row * T_SEQ + s0 + cswz * 8,
            &Vs[buf][(w * 16 + i * 8) * 64]);
    }
  };

  stage(0, 0);
  __syncthreads();

  for (int it = 0; it < nt; ++it) {
    const int buf = it & 1;
    if (it + 1 < nt) stage(buf ^ 1, (it + 1) * 64);

    // ---- QK^T: 4 col-tiles x (K=64 as 2 slices)
    f32x4 s[4];
#pragma unroll
    for (int c = 0; c < 4; ++c) {
      const bf16x8 kb0 = lds_frag(Ks[buf], c * 16 + lo, hi);
      const bf16x8 kb1 = lds_frag(Ks[buf], c * 16 + lo, 4 + hi);
      f32x4 a = (f32x4)0.f;
      a = __builtin_amdgcn_mfma_f32_16x16x32_bf16(qa0, kb0, a, 0, 0, 0);
      a = __builtin_amdgcn_mfma_f32_16x16x32_bf16(qa1, kb1, a, 0, 0, 0);
      s[c] = a;
    }

    // ---- causal mask (diagonal tile only; s0 == qt*64 there)
    if (it == nt - 1) {
#pragma unroll
      for (int c = 0; c < 4; ++c) {
        const int sg = c * 16 + lo;
#pragma unroll
        for (int r = 0; r < 4; ++r) {
          const int qq = w * 16 + hi * 4 + r;
          if (sg > qq) s[c][r] = -1e30f;
        }
      }
    }

    // ---- online softmax (rows q = hi*4+r; cols spread over 16 lanes x 4 c)
    float pr[4][4], corr[4];
#pragma unroll
    for (int r = 0; r < 4; ++r) {
      float mx = fmaxf(fmaxf(s[0][r], s[1][r]), fmaxf(s[2][r], s[3][r]));
      mx = fmaxf(mx, __shfl_xor(mx, 1));
      mx = fmaxf(mx, __shfl_xor(mx, 2));
      mx = fmaxf(mx, __shfl_xor(mx, 4));
      mx = fmaxf(mx, __shfl_xor(mx, 8));
      const float mn = fmaxf(mrow[r], mx);
      corr[r] = __expf(mrow[r] - mn);
      mrow[r] = mn;
      float ps = 0.f;
#pragma unroll
      for (int c = 0; c < 4; ++c) {
        pr[c][r] = __expf(s[c][r] - mn);
        ps += pr[c][r];
      }
      ps += __shfl_xor(ps, 1);
      ps += __shfl_xor(ps, 2);
      ps += __shfl_xor(ps, 4);
      ps += __shfl_xor(ps, 8);
      lrow[r] = lrow[r] * corr[r] + ps;
    }
#pragma unroll
    for (int dt = 0; dt < 4; ++dt)
#pragma unroll
      for (int r = 0; r < 4; ++r) o[dt][r] *= corr[r];

    // ---- P: C-layout regs -> per-wave LDS (bf16, swizzled) -> A-fragments
    u16* pw = &Ps[w][0];
#pragma unroll
    for (int c = 0; c < 4; ++c) {
      const int schunk = c * 2 + (lo >> 3);
      const int sb = lo & 7;
#pragma unroll
      for (int r = 0; r < 4; ++r) {
        const int q = hi * 4 + r;
        pw[q * 64 + ((schunk ^ (q & 7)) * 8) + sb] = f2bf(pr[c][r]);
      }
    }
    const bf16x8 pa0 = lds_frag(pw, lo, hi);
    const bf16x8 pa1 = lds_frag(pw, lo, 4 + hi);

    // ---- PV: O[16q][64d] += P[16q][64s] * V[64s][64d]
#pragma unroll
    for (int dt = 0; dt < 4; ++dt) {
      const bf16x8 vb0 = lds_frag(Vs[buf], dt * 16 + lo, hi);
      const bf16x8 vb1 = lds_frag(Vs[buf], dt * 16 + lo, 4 + hi);
      o[dt] = __builtin_amdgcn_mfma_f32_16x16x32_bf16(pa0, vb0, o[dt], 0, 0, 0);
      o[dt] = __builtin_amdgcn_mfma_f32_16x16x32_bf16(pa1, vb1, o[dt], 0, 0, 0);
    }
    __syncthreads();
  }

  // ---- epilogue: O/l -> ctx [B,T,H,64]
  const int b = bh >> 4, h = bh & 15;
  float inv[4];
#pragma unroll
  for (int r = 0; r < 4; ++r) inv[r] = 1.0f / lrow[r];
#pragma unroll
  for (int r = 0; r < 4; ++r) {
    const int t = qt * 64 + w * 16 + hi * 4 + r;
    u16* dst = ctx + ((size_t)(b * T_SEQ + t) * NHEAD + h) * 64;
#pragma unroll
    for (int dt = 0; dt < 4; ++dt) dst[dt * 16 + lo] = f2bf(o[dt][r] * inv[r]);
  }
}

// ---------------------------------------------------------------------------
// out = LayerNorm(x + y) * g + be  over last dim 1024. Optional bf16 copy.
// ---------------------------------------------------------------------------
template <bool EMIT_BF>
__global__ __launch_bounds__(256) void add_layernorm(
    const float* __restrict__ x, const float* __restrict__ y,
    const float* __restrict__ g, const float* __restrict__ be,
    float* __restrict__ out, u16* __restrict__ out_bf) {
  const int row = blockIdx.x;
  const int tid = threadIdx.x;
  const size_t base = (size_t)row * D_MODEL + tid * 4;

  const float4 xv = *(const float4*)&x[base];
  const float4 yv = *(const float4*)&y[base];
  const float v0 = xv.x + yv.x, v1 = xv.y + yv.y;
  const float v2 = xv.z + yv.z, v3 = xv.w + yv.w;

  float s = v0 + v1 + v2 + v3;
  float ss = v0 * v0 + v1 * v1 + v2 * v2 + v3 * v3;
#pragma unroll
  for (int off = 32; off > 0; off >>= 1) {
    s += __shfl_down(s, off);
    ss += __shfl_down(ss, off);
  }
  __shared__ float red[8];
  const int wid = tid >> 6, lane = tid & 63;
  if (lane == 0) { red[wid] = s; red[4 + wid] = ss; }
  __syncthreads();
  s = red[0] + red[1] + red[2] + red[3];
  ss = red[4] + red[5] + red[6] + red[7];

  const float mean = s * (1.0f / D_MODEL);
  const float var = ss * (1.0f / D_MODEL) - mean * mean;
  const float rr = rsqrtf(var + LN_EPS);

  const float4 g4 = *(const float4*)&g[tid * 4];
  const float4 b4 = *(const float4*)&be[tid * 4];
  float4 o4;
  o4.x = (v0 - mean) * rr * g4.x + b4.x;
  o4.y = (v1 - mean) * rr * g4.y + b4.y;
  o4.z = (v2 - mean) * rr * g4.z + b4.z;
  o4.w = (v3 - mean) * rr * g4.w + b4.w;
  *(float4*)&out[base] = o4;
  if (EMIT_BF) {
    ushort4 ob;
    ob.x = f2bf(o4.x); ob.y = f2bf(o4.y); ob.z = f2bf(o4.z); ob.w = f2bf(o4.w);
    *(ushort4*)&out_bf[base] = ob;
  }
}

// ---------------------------------------------------------------------------
extern "C" void kernel_launch(void* const* d_in, const int* in_sizes, int n_in,
                              void* d_out, int out_size, void* d_ws,
                              size_t ws_size, hipStream_t stream) {
  const float* x  = (const float*)d_in[0];
  const float* Wq = (const float*)d_in[1];
  const float* Wk = (const float*)d_in[2];
  const float* Wv = (const float*)d_in[3];
  const float* Wo = (const float*)d_in[4];
  const float* W1 = (const float*)d_in[5];
  const float* b1 = (const float*)d_in[6];
  const float* W2 = (const float*)d_in[7];
  const float* b2 = (const float*)d_in[8];
  const float* g1 = (const float*)d_in[9];
  const float* be1 = (const float*)d_in[10];
  const float* g2 = (const float*)d_in[11];
  const float* be2 = (const float*)d_in[12];

  char* ws = (char*)d_ws;
  const size_t MB = 1u << 20;
  u16*   x_bf    = (u16*)(ws + 0 * MB);     // 8MB
  u16*   WqT     = (u16*)(ws + 8 * MB);     // 2MB [n][k]
  u16*   WkT     = (u16*)(ws + 10 * MB);
  u16*   WvT     = (u16*)(ws + 12 * MB);
  u16*   WoB     = (u16*)(ws + 14 * MB);    // [n][k] already
  u16*   W1T     = (u16*)(ws + 16 * MB);    // 8MB
  u16*   W2T     = (u16*)(ws + 24 * MB);    // 8MB
  u16*   q_bf    = (u16*)(ws + 32 * MB);    // 8MB [B,H,T,64]
  u16*   k_bf    = (u16*)(ws + 40 * MB);    // 8MB [B,H,T,64]
  u16*   vT_bf   = (u16*)(ws + 48 * MB);    // 8MB [B,H,64,T]
  u16*   ctx_bf  = (u16*)(ws + 56 * MB);    // 8MB [B,T,H,64]
  float* attn    = (float*)(ws + 64 * MB);  // 16MB fp32
  float* h       = (float*)(ws + 80 * MB);  // 16MB fp32
  u16*   h_bf    = (u16*)(ws + 0 * MB);     // reuse x_bf (dead after QKV)
  u16*   ffn1_bf = (u16*)(ws + 32 * MB);    // 32MB, reuse q/k/vT/ctx
  float* ffn2    = (float*)(ws + 8 * MB);   // 16MB, reuse W[qkvo]T+W1T

  const dim3 blk(256);

  conv_f2b<<<NTOK * D_MODEL / 1024, blk, 0, stream>>>(x, x_bf, NTOK * D_MODEL);
  transpose_f2b<<<dim3(16, 16), blk, 0, stream>>>(Wq, WqT, D_MODEL, D_MODEL,
                                                  0.125f);  // fold qk scale
  transpose_f2b<<<dim3(16, 16), blk, 0, stream>>>(Wk, WkT, D_MODEL, D_MODEL, 1.f);
  transpose_f2b<<<dim3(16, 16), blk, 0, stream>>>(Wv, WvT, D_MODEL, D_MODEL, 1.f);
  conv_f2b<<<D_MODEL * D_MODEL / 1024, blk, 0, stream>>>(Wo, WoB,
                                                         D_MODEL * D_MODEL);
  transpose_f2b<<<dim3(64, 16), blk, 0, stream>>>(W1, W1T, D_MODEL, FF_DIM, 1.f);
  transpose_f2b<<<dim3(16, 64), blk, 0, stream>>>(W2, W2T, FF_DIM, D_MODEL, 1.f);

  const dim3 g1024(D_MODEL / 128, NTOK / 128);  // (8,32)
  const dim3 gff(FF_DIM / 128, NTOK / 128);     // (32,32)

  // QKV: bf16 outputs scattered into attention layouts (q scale folded in WqT)
  gemm_mfma<2, false, false><<<g1024, blk, 0, stream>>>(
      x_bf, WqT, nullptr, q_bf, NTOK, D_MODEL, D_MODEL, 1.f);
  gemm_mfma<2, false, false><<<g1024, blk, 0, stream>>>(
      x_bf, WkT, nullptr, k_bf, NTOK, D_MODEL, D_MODEL, 1.f);
  gemm_mfma<3, false, false><<<g1024, blk, 0, stream>>>(
      x_bf, WvT, nullptr, vT_bf, NTOK, D_MODEL, D_MODEL, 1.f);

  attn_mfma<<<dim3(T_SEQ / 64, 32), blk, 0, stream>>>(q_bf, k_bf, vT_bf,
                                                      ctx_bf);

  gemm_mfma<0, false, false><<<g1024, blk, 0, stream>>>(
      ctx_bf, WoB, nullptr, attn, NTOK, D_MODEL, D_MODEL, 1.f);

  add_layernorm<true><<<NTOK, blk, 0, stream>>>(x, attn, g1, be1, h, h_bf);

  gemm_mfma<1, true, true><<<gff, blk, 0, stream>>>(
      h_bf, W1T, b1, ffn1_bf, NTOK, FF_DIM, D_MODEL, 1.f);
  gemm_mfma<0, true, false><<<g1024, blk, 0, stream>>>(
      ffn1_bf, W2T, b2, ffn2, NTOK, D_MODEL, FF_DIM, 1.f);

  add_layernorm<false><<<NTOK, blk, 0, stream>>>(h, ffn2, g2, be2,
                                                 (float*)d_out, nullptr);
}

// Round 4
// 447.011 us; speedup vs baseline: 9.1042x; 1.1872x over previous
//
#include <hip/hip_runtime.h>
#include <math.h>

#define T_SEQ 2048
#define D_MODEL 1024
#define NHEAD 16
#define DHEAD 64
#define FF_DIM 4096
#define NTOK 4096   // B*T
#define LN_EPS 1e-6f

typedef unsigned short u16;
typedef __attribute__((ext_vector_type(8))) __bf16 bf16x8;
typedef __attribute__((ext_vector_type(4))) float f32x4;

typedef const void __attribute__((address_space(1))) gvoid;
typedef void __attribute__((address_space(3))) lvoid;

__device__ __forceinline__ u16 f2bf(float f) {
  unsigned u = __float_as_uint(f);
  return (u16)((u + 0x7fffu + ((u >> 16) & 1u)) >> 16);
}
__device__ __forceinline__ float bf2f(u16 u) {
  return __uint_as_float((unsigned)u << 16);
}

// async global(16B/lane) -> LDS; dest = wave-uniform base + lane*16B
__device__ __forceinline__ void gll16(const u16* g, u16* l) {
  __builtin_amdgcn_global_load_lds((gvoid*)g, (lvoid*)l, 16, 0, 0);
}

// read one 16B fragment from a [rows][64] bf16 LDS tile with chunk-XOR swizzle
__device__ __forceinline__ bf16x8 lds_frag(const u16* lds, int row, int chunk) {
  return *(const bf16x8*)&lds[row * 64 + ((chunk ^ (row & 7)) * 8)];
}

// ---------------------------------------------------------------------------
// fp32 -> bf16 flat convert (n % 1024 == 0)
// ---------------------------------------------------------------------------
__global__ __launch_bounds__(256) void conv_f2b(const float* __restrict__ in,
                                                u16* __restrict__ out, int n) {
  const int i = (blockIdx.x * 256 + threadIdx.x) * 4;
  if (i >= n) return;
  const float4 v = *(const float4*)&in[i];
  ushort4 o;
  o.x = f2bf(v.x); o.y = f2bf(v.y); o.z = f2bf(v.z); o.w = f2bf(v.w);
  *(ushort4*)&out[i] = o;
}

// ---------------------------------------------------------------------------
// fp32 [K,N] -> bf16 [N,K] transpose (optional scale). 64x64 tiles.
// ---------------------------------------------------------------------------
__global__ __launch_bounds__(256) void transpose_f2b(
    const float* __restrict__ in, u16* __restrict__ out, int K, int N,
    float scale) {
  __shared__ u16 t[64][72];
  const int tid = threadIdx.x;
  const int k0 = blockIdx.y * 64, n0 = blockIdx.x * 64;
  const int nl = tid & 63;
#pragma unroll
  for (int i = 0; i < 16; ++i) {
    const int kl = (tid >> 6) * 16 + i;
    t[nl][kl] = f2bf(in[(size_t)(k0 + kl) * N + n0 + nl] * scale);
  }
  __syncthreads();
  const int nr = tid >> 2, kc = (tid & 3) * 16;
  const uint4 a = *(const uint4*)&t[nr][kc];
  const uint4 b = *(const uint4*)&t[nr][kc + 8];
  *(uint4*)&out[(size_t)(n0 + nr) * K + k0 + kc] = a;
  *(uint4*)&out[(size_t)(n0 + nr) * K + k0 + kc + 8] = b;
}

// ---------------------------------------------------------------------------
// bf16 [B,H,T,64] -> bf16 [B,H,64,T]. grid (T/64, B*H)
// ---------------------------------------------------------------------------
__global__ __launch_bounds__(256) void transpose_v(const u16* __restrict__ vin,
                                                   u16* __restrict__ vout) {
  __shared__ u16 t[64][72];
  const int tid = threadIdx.x;
  const int bh = blockIdx.y;
  const int t0 = blockIdx.x * 64;
  const u16* src = vin + ((size_t)bh * T_SEQ + t0) * 64;
#pragma unroll
  for (int i = 0; i < 2; ++i) {
    const int r = i * 32 + (tid >> 3);
    const int ch = tid & 7;
    *(uint4*)&t[r][ch * 8] = *(const uint4*)&src[(size_t)r * 64 + ch * 8];
  }
  __syncthreads();
  const int d = tid >> 2, p = (tid & 3) * 16;
  alignas(16) u16 tmp[16];
#pragma unroll
  for (int i = 0; i < 16; ++i) tmp[i] = t[p + i][d];
  u16* dst = vout + ((size_t)bh * 64 + d) * T_SEQ + t0 + p;
  *(uint4*)&dst[0] = *(const uint4*)&tmp[0];
  *(uint4*)&dst[8] = *(const uint4*)&tmp[8];
}

// ---------------------------------------------------------------------------
// bf16 MFMA GEMM, 2-phase pipelined (single barrier/K-step), XCD-swizzled.
// C[m,n] = scale*sum_k A[m,k]*BT[n,k] (+bias)(relu)
// OUTMODE: 1 = bf16 [M,N] | 2 = qkv scatter: col<1024->q, <2048->k, else v,
//          each region bf16 [B,H,T,64] at C + region*4M elements.
// Grids must have (gx*gy)%8 == 0.
// ---------------------------------------------------------------------------
template <int OUTMODE, bool BIAS, bool RELU>
__global__ __launch_bounds__(256) void gemm_mfma(
    const u16* __restrict__ A, const u16* __restrict__ BT,
    const float* __restrict__ bias, void* __restrict__ C,
    int M, int N, int K, float scale) {
  __shared__ u16 smem[16384];  // [buf:2][A|B][128*32]

  const int tid = threadIdx.x;
  const int w = tid >> 6, lane = tid & 63;

  const int nwg = gridDim.x * gridDim.y;
  int bid = blockIdx.y * gridDim.x + blockIdx.x;
  const int cpx = nwg >> 3;
  bid = (bid & 7) * cpx + (bid >> 3);  // XCD-contiguous chunks
  const int bx = bid % gridDim.x, by = bid / gridDim.x;
  const int m0 = by * 128, n0 = bx * 128;
  const int wr = (w >> 1) * 64, wc = (w & 1) * 64;

  f32x4 acc[4][4];
#pragma unroll
  for (int i = 0; i < 4; ++i)
#pragma unroll
    for (int j = 0; j < 4; ++j) acc[i][j] = (f32x4)0.f;

  const int srow = w * 32 + (lane >> 2);
  const int scol = (lane & 3) * 8;
  const u16* gA0 = A + (size_t)(m0 + srow) * K + scol;
  const u16* gA1 = gA0 + (size_t)16 * K;
  const u16* gB0 = BT + (size_t)(n0 + srow) * K + scol;
  const u16* gB1 = gB0 + (size_t)16 * K;

  const int arow = lane & 15;
  const int koff = (lane >> 4) * 8;

  auto stage = [&](int buf, int k0) {
    u16* base = smem + buf * 8192;
    gll16(gA0 + k0, base + w * 1024);
    gll16(gA1 + k0, base + w * 1024 + 512);
    gll16(gB0 + k0, base + 4096 + w * 1024);
    gll16(gB1 + k0, base + 4096 + w * 1024 + 512);
  };

  stage(0, 0);
  __syncthreads();

  const int nk = K >> 5;
  for (int it = 0; it < nk; ++it) {
    const int buf = it & 1;
    if (it + 1 < nk) stage(buf ^ 1, (it + 1) << 5);

    const u16* sb = smem + buf * 8192;
    bf16x8 af[4], bff[4];
#pragma unroll
    for (int m = 0; m < 4; ++m)
      af[m] = *(const bf16x8*)&sb[(wr + m * 16 + arow) * 32 + koff];
#pragma unroll
    for (int n = 0; n < 4; ++n)
      bff[n] = *(const bf16x8*)&sb[4096 + (wc + n * 16 + arow) * 32 + koff];
#pragma unroll
    for (int m = 0; m < 4; ++m)
#pragma unroll
      for (int n = 0; n < 4; ++n)
        acc[m][n] = __builtin_amdgcn_mfma_f32_16x16x32_bf16(
            af[m], bff[n], acc[m][n], 0, 0, 0);
    __syncthreads();
  }

  // epilogue: D layout col=lane&15, row=(lane>>4)*4+reg  [m89-verified]
  const int rbase = (lane >> 4) * 4;
  const int cl = lane & 15;
#pragma unroll
  for (int n = 0; n < 4; ++n) {
    const int col = n0 + wc + n * 16 + cl;
    const float bia = BIAS ? bias[col] : 0.f;
#pragma unroll
    for (int m = 0; m < 4; ++m) {
      const int row0 = m0 + wr + m * 16 + rbase;
#pragma unroll
      for (int r = 0; r < 4; ++r) {
        float vv = acc[m][n][r] * scale + bia;
        if (RELU) vv = fmaxf(vv, 0.f);
        const int row = row0 + r;
        if (OUTMODE == 1) {
          ((u16*)C)[(size_t)row * N + col] = f2bf(vv);
        } else {
          const int reg = col >> 10, cl2 = col & 1023;
          const size_t off =
              (size_t)reg * 4194304 +
              ((size_t)((row >> 11) * NHEAD + (cl2 >> 6)) * T_SEQ +
               (row & 2047)) * 64 + (cl2 & 63);
          ((u16*)C)[off] = f2bf(vv);
        }
      }
    }
  }
}

// ---------------------------------------------------------------------------
// MFMA causal flash attention, QBLK=128 (wave = 32 q rows), exp2 domain.
// q,k: [B,H,T,64] bf16 (q pre-scaled by 0.125*log2e). vT: [B,H,64,T] bf16.
// ctx out: [B,T,H,64] bf16. Grid: (T/128, B*H), 256 thr (4 waves).
// ---------------------------------------------------------------------------
__global__ __launch_bounds__(256) void attn_mfma(
    const u16* __restrict__ qg, const u16* __restrict__ kg,
    const u16* __restrict__ vtg, u16* __restrict__ ctx) {
  __shared__ u16 Ks[2][64 * 64];
  __shared__ u16 Vs[2][64 * 64];
  __shared__ u16 Ps[4][32 * 64];

  const int tid = threadIdx.x;
  const int w = tid >> 6, lane = tid & 63;
  const int qt = gridDim.x - 1 - blockIdx.x;  // big blocks first
  const int bh = blockIdx.y;
  const int lo = lane & 15, hi = lane >> 4;
  const int r8 = lane >> 3, cswz = (lane & 7) ^ r8;

  const u16* qhead = qg + (size_t)bh * (T_SEQ * 64);
  const u16* khead = kg + (size_t)bh * (T_SEQ * 64);
  const u16* vhead = vtg + (size_t)bh * (64 * T_SEQ);

  const int qbase = qt * 128;
  const int q0w = qbase + w * 32;
  bf16x8 qa[2][2];
#pragma unroll
  for (int u = 0; u < 2; ++u) {
    const u16* qr = &qhead[(size_t)(q0w + u * 16 + lo) * 64];
    qa[u][0] = *(const bf16x8*)&qr[hi * 8];
    qa[u][1] = *(const bf16x8*)&qr[32 + hi * 8];
  }

  f32x4 o[2][4];
#pragma unroll
  for (int u = 0; u < 2; ++u)
#pragma unroll
    for (int dt = 0; dt < 4; ++dt) o[u][dt] = (f32x4)0.f;
  float mrow[2][4], lrow[2][4];
#pragma unroll
  for (int u = 0; u < 2; ++u)
#pragma unroll
    for (int r = 0; r < 4; ++r) { mrow[u][r] = -INFINITY; lrow[u][r] = 0.f; }

  const int nt = 2 * qt + 2;

  auto stage = [&](int buf, int s0) {
#pragma unroll
    for (int i = 0; i < 2; ++i) {
      const int row = w * 16 + i * 8 + r8;
      gll16(khead + (size_t)(s0 + row) * 64 + cswz * 8,
            &Ks[buf][(w * 16 + i * 8) * 64]);
      gll16(vhead + (size_t)row * T_SEQ + s0 + cswz * 8,
            &Vs[buf][(w * 16 + i * 8) * 64]);
    }
  };

  stage(0, 0);
  __syncthreads();

  for (int it = 0; it < nt; ++it) {
    const int buf = it & 1;
    if (it + 1 < nt) stage(buf ^ 1, (it + 1) * 64);

    const bool lastT = (it == nt - 1), diagT = (it == nt - 2);
    if (!(lastT && w < 2)) {  // waves 0,1 fully masked on final tile
      // ---- QK^T (16 MFMA)
      f32x4 s[2][4];
      __builtin_amdgcn_s_setprio(1);
#pragma unroll
      for (int c = 0; c < 4; ++c) {
        const bf16x8 kb0 = lds_frag(Ks[buf], c * 16 + lo, hi);
        const bf16x8 kb1 = lds_frag(Ks[buf], c * 16 + lo, 4 + hi);
#pragma unroll
        for (int u = 0; u < 2; ++u) {
          f32x4 a = (f32x4)0.f;
          a = __builtin_amdgcn_mfma_f32_16x16x32_bf16(qa[u][0], kb0, a, 0, 0, 0);
          a = __builtin_amdgcn_mfma_f32_16x16x32_bf16(qa[u][1], kb1, a, 0, 0, 0);
          s[u][c] = a;
        }
      }
      __builtin_amdgcn_s_setprio(0);

      // ---- causal mask on diagonal tiles
      if ((diagT && w < 2) || (lastT && w >= 2)) {
#pragma unroll
        for (int c = 0; c < 4; ++c) {
          const int sg = c * 16 + lo;
#pragma unroll
          for (int u = 0; u < 2; ++u)
#pragma unroll
            for (int r = 0; r < 4; ++r) {
              const int rl = (w * 32 + u * 16 + hi * 4 + r) & 63;
              if (sg > rl) s[u][c][r] = -1e30f;
            }
        }
      }

      // ---- online softmax (exp2 domain), defer-max (T13)
      float mx[2][4];
      bool myok = true;
#pragma unroll
      for (int u = 0; u < 2; ++u)
#pragma unroll
        for (int r = 0; r < 4; ++r) {
          float m4 = fmaxf(fmaxf(s[u][0][r], s[u][1][r]),
                           fmaxf(s[u][2][r], s[u][3][r]));
          m4 = fmaxf(m4, __shfl_xor(m4, 1));
          m4 = fmaxf(m4, __shfl_xor(m4, 2));
          m4 = fmaxf(m4, __shfl_xor(m4, 4));
          m4 = fmaxf(m4, __shfl_xor(m4, 8));
          mx[u][r] = m4;
          myok = myok && (m4 <= mrow[u][r] + 11.5f);
        }
      float corr[2][4];
#pragma unroll
      for (int u = 0; u < 2; ++u)
#pragma unroll
        for (int r = 0; r < 4; ++r) corr[u][r] = 1.f;
      if (!__all(myok)) {
#pragma unroll
        for (int u = 0; u < 2; ++u)
#pragma unroll
          for (int r = 0; r < 4; ++r) {
            const float mn = fmaxf(mrow[u][r], mx[u][r]);
            corr[u][r] = exp2f(mrow[u][r] - mn);
            mrow[u][r] = mn;
          }
#pragma unroll
        for (int u = 0; u < 2; ++u)
#pragma unroll
          for (int dt = 0; dt < 4; ++dt)
#pragma unroll
            for (int r = 0; r < 4; ++r) o[u][dt][r] *= corr[u][r];
      }
      float pr[2][4][4];
#pragma unroll
      for (int u = 0; u < 2; ++u)
#pragma unroll
        for (int r = 0; r < 4; ++r) {
          float ps = 0.f;
#pragma unroll
          for (int c = 0; c < 4; ++c) {
            pr[u][c][r] = exp2f(s[u][c][r] - mrow[u][r]);
            ps += pr[u][c][r];
          }
          ps += __shfl_xor(ps, 1);
          ps += __shfl_xor(ps, 2);
          ps += __shfl_xor(ps, 4);
          ps += __shfl_xor(ps, 8);
          lrow[u][r] = lrow[u][r] * corr[u][r] + ps;
        }

      // ---- P: C-layout regs -> per-wave LDS (swizzled) -> A-fragments
      u16* pw = &Ps[w][0];
#pragma unroll
      for (int c = 0; c < 4; ++c) {
        const int schunk = c * 2 + (lo >> 3);
        const int sb = lo & 7;
#pragma unroll
        for (int u = 0; u < 2; ++u)
#pragma unroll
          for (int r = 0; r < 4; ++r) {
            const int rw = u * 16 + hi * 4 + r;
            pw[rw * 64 + ((schunk ^ (rw & 7)) * 8) + sb] = f2bf(pr[u][c][r]);
          }
      }
      bf16x8 pa[2][2];
#pragma unroll
      for (int u = 0; u < 2; ++u) {
        pa[u][0] = lds_frag(pw, u * 16 + lo, hi);
        pa[u][1] = lds_frag(pw, u * 16 + lo, 4 + hi);
      }

      // ---- PV (16 MFMA)
      __builtin_amdgcn_s_setprio(1);
#pragma unroll
      for (int dt = 0; dt < 4; ++dt) {
        const bf16x8 vb0 = lds_frag(Vs[buf], dt * 16 + lo, hi);
        const bf16x8 vb1 = lds_frag(Vs[buf], dt * 16 + lo, 4 + hi);
#pragma unroll
        for (int u = 0; u < 2; ++u) {
          o[u][dt] = __builtin_amdgcn_mfma_f32_16x16x32_bf16(pa[u][0], vb0,
                                                             o[u][dt], 0, 0, 0);
          o[u][dt] = __builtin_amdgcn_mfma_f32_16x16x32_bf16(pa[u][1], vb1,
                                                             o[u][dt], 0, 0, 0);
        }
      }
      __builtin_amdgcn_s_setprio(0);
    }
    __syncthreads();
  }

  // ---- epilogue: O/l -> ctx [B,T,H,64]
  const int b = bh >> 4, h = bh & 15;
#pragma unroll
  for (int u = 0; u < 2; ++u)
#pragma unroll
    for (int r = 0; r < 4; ++r) {
      const float inv = 1.0f / lrow[u][r];
      const int t = qbase + w * 32 + u * 16 + hi * 4 + r;
      u16* dst = ctx + ((size_t)(b * T_SEQ + t) * NHEAD + h) * 64;
#pragma unroll
      for (int dt = 0; dt < 4; ++dt)
        dst[dt * 16 + lo] = f2bf(o[u][dt][r] * inv);
    }
}

// ---------------------------------------------------------------------------
// out = LayerNorm(x + y) * g + be over last dim 1024. y is bf16.
// ---------------------------------------------------------------------------
template <bool EMIT_BF>
__global__ __launch_bounds__(256) void add_layernorm(
    const float* __restrict__ x, const u16* __restrict__ y,
    const float* __restrict__ g, const float* __restrict__ be,
    float* __restrict__ out, u16* __restrict__ out_bf) {
  const int row = blockIdx.x;
  const int tid = threadIdx.x;
  const size_t base = (size_t)row * D_MODEL + tid * 4;

  const float4 xv = *(const float4*)&x[base];
  const ushort4 yv = *(const ushort4*)&y[base];
  const float v0 = xv.x + bf2f(yv.x), v1 = xv.y + bf2f(yv.y);
  const float v2 = xv.z + bf2f(yv.z), v3 = xv.w + bf2f(yv.w);

  float s = v0 + v1 + v2 + v3;
  float ss = v0 * v0 + v1 * v1 + v2 * v2 + v3 * v3;
#pragma unroll
  for (int off = 32; off > 0; off >>= 1) {
    s += __shfl_down(s, off);
    ss += __shfl_down(ss, off);
  }
  __shared__ float red[8];
  const int wid = tid >> 6, lane = tid & 63;
  if (lane == 0) { red[wid] = s; red[4 + wid] = ss; }
  __syncthreads();
  s = red[0] + red[1] + red[2] + red[3];
  ss = red[4] + red[5] + red[6] + red[7];

  const float mean = s * (1.0f / D_MODEL);
  const float var = ss * (1.0f / D_MODEL) - mean * mean;
  const float rr = rsqrtf(var + LN_EPS);

  const float4 g4 = *(const float4*)&g[tid * 4];
  const float4 b4 = *(const float4*)&be[tid * 4];
  float4 o4;
  o4.x = (v0 - mean) * rr * g4.x + b4.x;
  o4.y = (v1 - mean) * rr * g4.y + b4.y;
  o4.z = (v2 - mean) * rr * g4.z + b4.z;
  o4.w = (v3 - mean) * rr * g4.w + b4.w;
  *(float4*)&out[base] = o4;
  if (EMIT_BF) {
    ushort4 ob;
    ob.x = f2bf(o4.x); ob.y = f2bf(o4.y); ob.z = f2bf(o4.z); ob.w = f2bf(o4.w);
    *(ushort4*)&out_bf[base] = ob;
  }
}

// ---------------------------------------------------------------------------
extern "C" void kernel_launch(void* const* d_in, const int* in_sizes, int n_in,
                              void* d_out, int out_size, void* d_ws,
                              size_t ws_size, hipStream_t stream) {
  const float* x  = (const float*)d_in[0];
  const float* Wq = (const float*)d_in[1];
  const float* Wk = (const float*)d_in[2];
  const float* Wv = (const float*)d_in[3];
  const float* Wo = (const float*)d_in[4];
  const float* W1 = (const float*)d_in[5];
  const float* b1 = (const float*)d_in[6];
  const float* W2 = (const float*)d_in[7];
  const float* b2 = (const float*)d_in[8];
  const float* g1 = (const float*)d_in[9];
  const float* be1 = (const float*)d_in[10];
  const float* g2 = (const float*)d_in[11];
  const float* be2 = (const float*)d_in[12];

  char* ws = (char*)d_ws;
  const size_t MB = 1u << 20;
  u16*   x_bf    = (u16*)(ws + 0 * MB);     // 8MB [4096][1024]
  u16*   WqkvT   = (u16*)(ws + 8 * MB);     // 6MB [3072][1024]
  u16*   WoB     = (u16*)(ws + 14 * MB);    // 2MB [1024][1024] (n,k)
  u16*   W1T     = (u16*)(ws + 16 * MB);    // 8MB [4096][1024]
  u16*   W2T     = (u16*)(ws + 24 * MB);    // 8MB [1024][4096]
  u16*   q_bf    = (u16*)(ws + 32 * MB);    // 8MB [B,H,T,64]  (qkv contiguous)
  u16*   v_bf    = (u16*)(ws + 48 * MB);    // 8MB [B,H,T,64]
  u16*   vT_bf   = (u16*)(ws + 56 * MB);    // 8MB [B,H,64,T]
  u16*   ctx_bf  = (u16*)(ws + 64 * MB);    // 8MB [B,T,H,64]
  u16*   attn_bf = (u16*)(ws + 72 * MB);    // 8MB [4096][1024]
  float* h       = (float*)(ws + 80 * MB);  // 16MB fp32
  u16*   h_bf    = (u16*)(ws + 0 * MB);     // reuse x_bf (dead after QKV)
  u16*   ffn1_bf = (u16*)(ws + 32 * MB);    // 32MB reuse q/k/v/vT
  u16*   ffn2_bf = (u16*)(ws + 8 * MB);     // 8MB reuse WqkvT

  const dim3 blk(256);
  const float lg2e = 1.44269504f;

  conv_f2b<<<NTOK, blk, 0, stream>>>(x, x_bf, NTOK * D_MODEL);
  // fold 1/sqrt(dk) * log2(e) into Wq so QK scores land in exp2 domain
  transpose_f2b<<<dim3(16, 16), blk, 0, stream>>>(Wq, WqkvT, D_MODEL, D_MODEL,
                                                  0.125f * lg2e);
  transpose_f2b<<<dim3(16, 16), blk, 0, stream>>>(Wk, WqkvT + 1024 * 1024,
                                                  D_MODEL, D_MODEL, 1.f);
  transpose_f2b<<<dim3(16, 16), blk, 0, stream>>>(Wv, WqkvT + 2 * 1024 * 1024,
                                                  D_MODEL, D_MODEL, 1.f);
  conv_f2b<<<1024, blk, 0, stream>>>(Wo, WoB, D_MODEL * D_MODEL);
  transpose_f2b<<<dim3(64, 16), blk, 0, stream>>>(W1, W1T, D_MODEL, FF_DIM, 1.f);
  transpose_f2b<<<dim3(16, 64), blk, 0, stream>>>(W2, W2T, FF_DIM, D_MODEL, 1.f);

  // merged QKV projection: [4096,1024] x [3072,1024]^T -> scatter q/k/v
  gemm_mfma<2, false, false><<<dim3(24, 32), blk, 0, stream>>>(
      x_bf, WqkvT, nullptr, q_bf, NTOK, 3072, D_MODEL, 1.f);

  transpose_v<<<dim3(32, 32), blk, 0, stream>>>(v_bf, vT_bf);

  attn_mfma<<<dim3(T_SEQ / 128, 32), blk, 0, stream>>>(q_bf, q_bf + 4194304,
                                                       vT_bf, ctx_bf);

  gemm_mfma<1, false, false><<<dim3(8, 32), blk, 0, stream>>>(
      ctx_bf, WoB, nullptr, attn_bf, NTOK, D_MODEL, D_MODEL, 1.f);

  add_layernorm<true><<<NTOK, blk, 0, stream>>>(x, attn_bf, g1, be1, h, h_bf);

  gemm_mfma<1, true, true><<<dim3(32, 32), blk, 0, stream>>>(
      h_bf, W1T, b1, ffn1_bf, NTOK, FF_DIM, D_MODEL, 1.f);
  gemm_mfma<1, true, false><<<dim3(8, 32), blk, 0, stream>>>(
      ffn1_bf, W2T, b2, ffn2_bf, NTOK, D_MODEL, FF_DIM, 1.f);

  add_layernorm<false><<<NTOK, blk, 0, stream>>>(h, ffn2_bf, g2, be2,
                                                 (float*)d_out, nullptr);
}

// Round 5
// 401.385 us; speedup vs baseline: 10.1390x; 1.1137x over previous
//
#include <hip/hip_runtime.h>
#include <math.h>

#define T_SEQ 2048
#define D_MODEL 1024
#define NHEAD 16
#define DHEAD 64
#define FF_DIM 4096
#define NTOK 4096   // B*T
#define LN_EPS 1e-6f

typedef unsigned short u16;
typedef unsigned int u32;
typedef __attribute__((ext_vector_type(8))) __bf16 bf16x8;
typedef __attribute__((ext_vector_type(4))) float f32x4;
typedef __attribute__((ext_vector_type(16))) float f32x16;

typedef const void __attribute__((address_space(1))) gvoid;
typedef void __attribute__((address_space(3))) lvoid;

__device__ __forceinline__ u16 f2bf(float f) {
  unsigned u = __float_as_uint(f);
  return (u16)((u + 0x7fffu + ((u >> 16) & 1u)) >> 16);
}
__device__ __forceinline__ float bf2f(u16 u) {
  return __uint_as_float((unsigned)u << 16);
}
// v_cvt_pk_bf16_f32: pack 2 f32 -> 2 bf16 in one dword (lo, hi)
__device__ __forceinline__ u32 cvtpk(float lo, float hi) {
  u32 r;
  asm("v_cvt_pk_bf16_f32 %0, %1, %2" : "=v"(r) : "v"(lo), "v"(hi));
  return r;
}

// async global(16B/lane) -> LDS; dest = wave-uniform base + lane*16B
__device__ __forceinline__ void gll16(const u16* g, u16* l) {
  __builtin_amdgcn_global_load_lds((gvoid*)g, (lvoid*)l, 16, 0, 0);
}

// read one 16B fragment from a [rows][64] bf16 LDS tile with chunk-XOR swizzle
__device__ __forceinline__ bf16x8 lds_frag(const u16* lds, int row, int chunk) {
  return *(const bf16x8*)&lds[row * 64 + ((chunk ^ (row & 7)) * 8)];
}

union BF8 { u32 u[4]; bf16x8 v; };

// ---------------------------------------------------------------------------
// fp32 -> bf16 flat convert (n % 1024 == 0)
// ---------------------------------------------------------------------------
__global__ __launch_bounds__(256) void conv_f2b(const float* __restrict__ in,
                                                u16* __restrict__ out, int n) {
  const int i = (blockIdx.x * 256 + threadIdx.x) * 4;
  if (i >= n) return;
  const float4 v = *(const float4*)&in[i];
  ushort4 o;
  o.x = f2bf(v.x); o.y = f2bf(v.y); o.z = f2bf(v.z); o.w = f2bf(v.w);
  *(ushort4*)&out[i] = o;
}

// ---------------------------------------------------------------------------
// fp32 [K,N] -> bf16 [N,K] transpose (optional scale). 64x64 tiles.
// ---------------------------------------------------------------------------
__global__ __launch_bounds__(256) void transpose_f2b(
    const float* __restrict__ in, u16* __restrict__ out, int K, int N,
    float scale) {
  __shared__ u16 t[64][72];
  const int tid = threadIdx.x;
  const int k0 = blockIdx.y * 64, n0 = blockIdx.x * 64;
  const int nl = tid & 63;
#pragma unroll
  for (int i = 0; i < 16; ++i) {
    const int kl = (tid >> 6) * 16 + i;
    t[nl][kl] = f2bf(in[(size_t)(k0 + kl) * N + n0 + nl] * scale);
  }
  __syncthreads();
  const int nr = tid >> 2, kc = (tid & 3) * 16;
  const uint4 a = *(const uint4*)&t[nr][kc];
  const uint4 b = *(const uint4*)&t[nr][kc + 8];
  *(uint4*)&out[(size_t)(n0 + nr) * K + k0 + kc] = a;
  *(uint4*)&out[(size_t)(n0 + nr) * K + k0 + kc + 8] = b;
}

// ---------------------------------------------------------------------------
// bf16 [B,H,T,64] -> bf16 [B,H,64,T]. grid (T/64, B*H)
// ---------------------------------------------------------------------------
__global__ __launch_bounds__(256) void transpose_v(const u16* __restrict__ vin,
                                                   u16* __restrict__ vout) {
  __shared__ u16 t[64][72];
  const int tid = threadIdx.x;
  const int bh = blockIdx.y;
  const int t0 = blockIdx.x * 64;
  const u16* src = vin + ((size_t)bh * T_SEQ + t0) * 64;
#pragma unroll
  for (int i = 0; i < 2; ++i) {
    const int r = i * 32 + (tid >> 3);
    const int ch = tid & 7;
    *(uint4*)&t[r][ch * 8] = *(const uint4*)&src[(size_t)r * 64 + ch * 8];
  }
  __syncthreads();
  const int d = tid >> 2, p = (tid & 3) * 16;
  alignas(16) u16 tmp[16];
#pragma unroll
  for (int i = 0; i < 16; ++i) tmp[i] = t[p + i][d];
  u16* dst = vout + ((size_t)bh * 64 + d) * T_SEQ + t0 + p;
  *(uint4*)&dst[0] = *(const uint4*)&tmp[0];
  *(uint4*)&dst[8] = *(const uint4*)&tmp[8];
}

// ---------------------------------------------------------------------------
// bf16 MFMA GEMM, 2-phase pipelined (single barrier/K-step), XCD-swizzled.
// C[m,n] = scale*sum_k A[m,k]*BT[n,k] (+bias)(relu)
// OUTMODE: 1 = bf16 [M,N] | 2 = qkv scatter: col<1024->q, <2048->k, else v,
//          each region bf16 [B,H,T,64] at C + region*4M elements.
// Grids must have (gx*gy)%8 == 0.
// ---------------------------------------------------------------------------
template <int OUTMODE, bool BIAS, bool RELU>
__global__ __launch_bounds__(256) void gemm_mfma(
    const u16* __restrict__ A, const u16* __restrict__ BT,
    const float* __restrict__ bias, void* __restrict__ C,
    int M, int N, int K, float scale) {
  __shared__ u16 smem[16384];  // [buf:2][A|B][128*32]

  const int tid = threadIdx.x;
  const int w = tid >> 6, lane = tid & 63;

  const int nwg = gridDim.x * gridDim.y;
  int bid = blockIdx.y * gridDim.x + blockIdx.x;
  const int cpx = nwg >> 3;
  bid = (bid & 7) * cpx + (bid >> 3);  // XCD-contiguous chunks
  const int bx = bid % gridDim.x, by = bid / gridDim.x;
  const int m0 = by * 128, n0 = bx * 128;
  const int wr = (w >> 1) * 64, wc = (w & 1) * 64;

  f32x4 acc[4][4];
#pragma unroll
  for (int i = 0; i < 4; ++i)
#pragma unroll
    for (int j = 0; j < 4; ++j) acc[i][j] = (f32x4)0.f;

  const int srow = w * 32 + (lane >> 2);
  const int scol = (lane & 3) * 8;
  const u16* gA0 = A + (size_t)(m0 + srow) * K + scol;
  const u16* gA1 = gA0 + (size_t)16 * K;
  const u16* gB0 = BT + (size_t)(n0 + srow) * K + scol;
  const u16* gB1 = gB0 + (size_t)16 * K;

  const int arow = lane & 15;
  const int koff = (lane >> 4) * 8;

  auto stage = [&](int buf, int k0) {
    u16* base = smem + buf * 8192;
    gll16(gA0 + k0, base + w * 1024);
    gll16(gA1 + k0, base + w * 1024 + 512);
    gll16(gB0 + k0, base + 4096 + w * 1024);
    gll16(gB1 + k0, base + 4096 + w * 1024 + 512);
  };

  stage(0, 0);
  __syncthreads();

  const int nk = K >> 5;
  for (int it = 0; it < nk; ++it) {
    const int buf = it & 1;
    if (it + 1 < nk) stage(buf ^ 1, (it + 1) << 5);

    const u16* sb = smem + buf * 8192;
    bf16x8 af[4], bff[4];
#pragma unroll
    for (int m = 0; m < 4; ++m)
      af[m] = *(const bf16x8*)&sb[(wr + m * 16 + arow) * 32 + koff];
#pragma unroll
    for (int n = 0; n < 4; ++n)
      bff[n] = *(const bf16x8*)&sb[4096 + (wc + n * 16 + arow) * 32 + koff];
#pragma unroll
    for (int m = 0; m < 4; ++m)
#pragma unroll
      for (int n = 0; n < 4; ++n)
        acc[m][n] = __builtin_amdgcn_mfma_f32_16x16x32_bf16(
            af[m], bff[n], acc[m][n], 0, 0, 0);
    __syncthreads();
  }

  // epilogue: D layout col=lane&15, row=(lane>>4)*4+reg  [m89-verified]
  const int rbase = (lane >> 4) * 4;
  const int cl = lane & 15;
#pragma unroll
  for (int n = 0; n < 4; ++n) {
    const int col = n0 + wc + n * 16 + cl;
    const float bia = BIAS ? bias[col] : 0.f;
#pragma unroll
    for (int m = 0; m < 4; ++m) {
      const int row0 = m0 + wr + m * 16 + rbase;
#pragma unroll
      for (int r = 0; r < 4; ++r) {
        float vv = acc[m][n][r] * scale + bia;
        if (RELU) vv = fmaxf(vv, 0.f);
        const int row = row0 + r;
        if (OUTMODE == 1) {
          ((u16*)C)[(size_t)row * N + col] = f2bf(vv);
        } else {
          const int reg = col >> 10, cl2 = col & 1023;
          const size_t off =
              (size_t)reg * 4194304 +
              ((size_t)((row >> 11) * NHEAD + (cl2 >> 6)) * T_SEQ +
               (row & 2047)) * 64 + (cl2 & 63);
          ((u16*)C)[off] = f2bf(vv);
        }
      }
    }
  }
}

// ---------------------------------------------------------------------------
// MFMA causal flash attention, swapped-operand (T12): lane owns one q-row.
// q,k: [B,H,T,64] bf16 (q pre-scaled by 0.125*log2e). vT: [B,H,64,T] bf16.
// ctx out: [B,T,H,64] bf16. Grid: (T/128, B*H), 256 thr; wave = 32 q rows.
// QK^T = mfma(K, Q) -> S^T[s][q]; PV = mfma(V^T, P^T) -> O^T[d][q].
// ---------------------------------------------------------------------------
__global__ __launch_bounds__(256) void attn_mfma(
    const u16* __restrict__ qg, const u16* __restrict__ kg,
    const u16* __restrict__ vtg, u16* __restrict__ ctx) {
  __shared__ u16 Ks[2][64 * 64];
  __shared__ u16 Vs[2][64 * 64];

  const int tid = threadIdx.x;
  const int w = tid >> 6, lane = tid & 63;
  const int qt = gridDim.x - 1 - blockIdx.x;  // big blocks first
  const int bh = blockIdx.y;
  const int l31 = lane & 31, hi32 = lane >> 5;
  const int r8 = lane >> 3, cswz = (lane & 7) ^ r8;

  const u16* qhead = qg + (size_t)bh * (T_SEQ * 64);
  const u16* khead = kg + (size_t)bh * (T_SEQ * 64);
  const u16* vhead = vtg + (size_t)bh * (64 * T_SEQ);

  const int qbase = qt * 128;
  const int qrow = qbase + w * 32 + l31;  // this lane's q row (global t)

  // Q B-fragments (col=l31, k = ks2*16 + hi32*8 + i), resident all kernel
  bf16x8 qb[4];
#pragma unroll
  for (int ks2 = 0; ks2 < 4; ++ks2)
    qb[ks2] = *(const bf16x8*)&qhead[(size_t)qrow * 64 + ks2 * 16 + hi32 * 8];

  f32x16 o0 = (f32x16)0.f, o1 = (f32x16)0.f;  // O^T: d = dv*32 + rowmap
  float m = -INFINITY, l = 0.f;

  const int nt = 2 * qt + 2;

  auto stage = [&](int buf, int s0) {
#pragma unroll
    for (int i = 0; i < 2; ++i) {
      const int row = w * 16 + i * 8 + r8;
      gll16(khead + (size_t)(s0 + row) * 64 + cswz * 8,
            &Ks[buf][(w * 16 + i * 8) * 64]);
      gll16(vhead + (size_t)row * T_SEQ + s0 + cswz * 8,
            &Vs[buf][(w * 16 + i * 8) * 64]);
    }
  };

  stage(0, 0);
  __syncthreads();

  for (int it = 0; it < nt; ++it) {
    const int buf = it & 1;
    if (it + 1 < nt) stage(buf ^ 1, (it + 1) * 64);

    const bool lastT = (it == nt - 1), diagT = (it == nt - 2);
    if (!(lastT && w < 2)) {  // waves 0,1 fully masked on final tile
      // ---- QK^T: S^T[s=sub*32+rowmap][q=l31], 8 MFMA 32x32x16
      f32x16 st0 = (f32x16)0.f, st1 = (f32x16)0.f;
      __builtin_amdgcn_s_setprio(1);
#pragma unroll
      for (int ks2 = 0; ks2 < 4; ++ks2) {
        const bf16x8 kf0 = lds_frag(Ks[buf], l31, ks2 * 2 + hi32);
        st0 = __builtin_amdgcn_mfma_f32_32x32x16_bf16(kf0, qb[ks2], st0, 0, 0, 0);
      }
#pragma unroll
      for (int ks2 = 0; ks2 < 4; ++ks2) {
        const bf16x8 kf1 = lds_frag(Ks[buf], 32 + l31, ks2 * 2 + hi32);
        st1 = __builtin_amdgcn_mfma_f32_32x32x16_bf16(kf1, qb[ks2], st1, 0, 0, 0);
      }
      __builtin_amdgcn_s_setprio(0);

      // ---- causal mask (diagonal tiles only)
      if ((diagT && w < 2) || (lastT && w >= 2)) {
        const int s0g = it * 64;
#pragma unroll
        for (int r = 0; r < 16; ++r) {
          const int rowm = (r & 3) + 8 * (r >> 2) + 4 * hi32;
          if (s0g + rowm > qrow) st0[r] = -1e30f;
          if (s0g + 32 + rowm > qrow) st1[r] = -1e30f;
        }
      }

      // ---- online softmax (exp2 domain): s-axis is lane-local + 1 swap
      float mx = fmaxf(st0[0], st1[0]);
#pragma unroll
      for (int r = 1; r < 16; ++r) mx = fmaxf(mx, fmaxf(st0[r], st1[r]));
      mx = fmaxf(mx, __shfl_xor(mx, 32));

      float corr = 1.f;
      if (!__all(mx <= m + 11.5f)) {  // defer-max (T13)
        const float mn = fmaxf(m, mx);
        corr = exp2f(m - mn);
        m = mn;
#pragma unroll
        for (int r = 0; r < 16; ++r) { o0[r] *= corr; o1[r] *= corr; }
      }
      float ps = 0.f;
#pragma unroll
      for (int r = 0; r < 16; ++r) {
        st0[r] = exp2f(st0[r] - m);
        st1[r] = exp2f(st1[r] - m);
        ps += st0[r] + st1[r];
      }
      ps += __shfl_xor(ps, 32);
      l = l * corr + ps;

      // ---- P^T B-fragments in-register: cvt_pk + permlane32_swap (T12)
      BF8 pb[4];
#pragma unroll
      for (int blk = 0; blk < 2; ++blk) {
        {
          u32 x0 = cvtpk(st0[blk * 8 + 0], st0[blk * 8 + 1]);
          u32 x1 = cvtpk(st0[blk * 8 + 2], st0[blk * 8 + 3]);
          u32 y0 = cvtpk(st0[blk * 8 + 4], st0[blk * 8 + 5]);
          u32 y1 = cvtpk(st0[blk * 8 + 6], st0[blk * 8 + 7]);
          asm("v_permlane32_swap_b32 %0, %1" : "+v"(x0), "+v"(y0));
          asm("v_permlane32_swap_b32 %0, %1" : "+v"(x1), "+v"(y1));
          pb[blk].u[0] = x0; pb[blk].u[1] = x1;
          pb[blk].u[2] = y0; pb[blk].u[3] = y1;
        }
        {
          u32 x0 = cvtpk(st1[blk * 8 + 0], st1[blk * 8 + 1]);
          u32 x1 = cvtpk(st1[blk * 8 + 2], st1[blk * 8 + 3]);
          u32 y0 = cvtpk(st1[blk * 8 + 4], st1[blk * 8 + 5]);
          u32 y1 = cvtpk(st1[blk * 8 + 6], st1[blk * 8 + 7]);
          asm("v_permlane32_swap_b32 %0, %1" : "+v"(x0), "+v"(y0));
          asm("v_permlane32_swap_b32 %0, %1" : "+v"(x1), "+v"(y1));
          pb[2 + blk].u[0] = x0; pb[2 + blk].u[1] = x1;
          pb[2 + blk].u[2] = y0; pb[2 + blk].u[3] = y1;
        }
      }

      // ---- PV: O^T[d][q] += V^T[d][s] * P^T[s][q], 8 MFMA
      __builtin_amdgcn_s_setprio(1);
#pragma unroll
      for (int ks = 0; ks < 4; ++ks) {
        const bf16x8 vf0 = lds_frag(Vs[buf], l31, ks * 2 + hi32);
        o0 = __builtin_amdgcn_mfma_f32_32x32x16_bf16(vf0, pb[ks].v, o0, 0, 0, 0);
      }
#pragma unroll
      for (int ks = 0; ks < 4; ++ks) {
        const bf16x8 vf1 = lds_frag(Vs[buf], 32 + l31, ks * 2 + hi32);
        o1 = __builtin_amdgcn_mfma_f32_32x32x16_bf16(vf1, pb[ks].v, o1, 0, 0, 0);
      }
      __builtin_amdgcn_s_setprio(0);
    }
    __syncthreads();
  }

  // ---- epilogue: normalize, transpose O^T->O via per-wave LDS, store ctx
  const float inv = 1.0f / l;
#pragma unroll
  for (int r = 0; r < 16; ++r) { o0[r] *= inv; o1[r] *= inv; }

  u16* ep = &Ks[0][0] + w * 2048;  // per-wave 32q x 64d bf16, chunk-swizzled
#pragma unroll
  for (int rg = 0; rg < 4; ++rg) {
    const u32 w0 = cvtpk(o0[rg * 4 + 0], o0[rg * 4 + 1]);
    const u32 w1 = cvtpk(o0[rg * 4 + 2], o0[rg * 4 + 3]);
    uint2 val; val.x = w0; val.y = w1;
    *(uint2*)&ep[l31 * 64 + ((rg ^ (l31 & 7)) * 8) + hi32 * 4] = val;
  }
#pragma unroll
  for (int rg = 0; rg < 4; ++rg) {
    const u32 w0 = cvtpk(o1[rg * 4 + 0], o1[rg * 4 + 1]);
    const u32 w1 = cvtpk(o1[rg * 4 + 2], o1[rg * 4 + 3]);
    const int chunk = 4 + rg;
    uint2 val; val.x = w0; val.y = w1;
    *(uint2*)&ep[l31 * 64 + ((chunk ^ (l31 & 7)) * 8) + hi32 * 4] = val;
  }

  const int b = bh >> 4, h = bh & 15;
  const int ql = lane >> 1, half = lane & 1;
  const int t = qbase + w * 32 + ql;
  u16* dst = ctx + ((size_t)(b * T_SEQ + t) * NHEAD + h) * 64;
#pragma unroll
  for (int j = 0; j < 4; ++j) {
    const int chunk = half * 4 + j;
    const uint4 vv = *(const uint4*)&ep[ql * 64 + ((chunk ^ (ql & 7)) * 8)];
    *(uint4*)&dst[chunk * 8] = vv;
  }
}

// ---------------------------------------------------------------------------
// out = LayerNorm(x + y) * g + be over last dim 1024. y is bf16.
// ---------------------------------------------------------------------------
template <bool EMIT_BF>
__global__ __launch_bounds__(256) void add_layernorm(
    const float* __restrict__ x, const u16* __restrict__ y,
    const float* __restrict__ g, const float* __restrict__ be,
    float* __restrict__ out, u16* __restrict__ out_bf) {
  const int row = blockIdx.x;
  const int tid = threadIdx.x;
  const size_t base = (size_t)row * D_MODEL + tid * 4;

  const float4 xv = *(const float4*)&x[base];
  const ushort4 yv = *(const ushort4*)&y[base];
  const float v0 = xv.x + bf2f(yv.x), v1 = xv.y + bf2f(yv.y);
  const float v2 = xv.z + bf2f(yv.z), v3 = xv.w + bf2f(yv.w);

  float s = v0 + v1 + v2 + v3;
  float ss = v0 * v0 + v1 * v1 + v2 * v2 + v3 * v3;
#pragma unroll
  for (int off = 32; off > 0; off >>= 1) {
    s += __shfl_down(s, off);
    ss += __shfl_down(ss, off);
  }
  __shared__ float red[8];
  const int wid = tid >> 6, lane = tid & 63;
  if (lane == 0) { red[wid] = s; red[4 + wid] = ss; }
  __syncthreads();
  s = red[0] + red[1] + red[2] + red[3];
  ss = red[4] + red[5] + red[6] + red[7];

  const float mean = s * (1.0f / D_MODEL);
  const float var = ss * (1.0f / D_MODEL) - mean * mean;
  const float rr = rsqrtf(var + LN_EPS);

  const float4 g4 = *(const float4*)&g[tid * 4];
  const float4 b4 = *(const float4*)&be[tid * 4];
  float4 o4;
  o4.x = (v0 - mean) * rr * g4.x + b4.x;
  o4.y = (v1 - mean) * rr * g4.y + b4.y;
  o4.z = (v2 - mean) * rr * g4.z + b4.z;
  o4.w = (v3 - mean) * rr * g4.w + b4.w;
  *(float4*)&out[base] = o4;
  if (EMIT_BF) {
    ushort4 ob;
    ob.x = f2bf(o4.x); ob.y = f2bf(o4.y); ob.z = f2bf(o4.z); ob.w = f2bf(o4.w);
    *(ushort4*)&out_bf[base] = ob;
  }
}

// ---------------------------------------------------------------------------
extern "C" void kernel_launch(void* const* d_in, const int* in_sizes, int n_in,
                              void* d_out, int out_size, void* d_ws,
                              size_t ws_size, hipStream_t stream) {
  const float* x  = (const float*)d_in[0];
  const float* Wq = (const float*)d_in[1];
  const float* Wk = (const float*)d_in[2];
  const float* Wv = (const float*)d_in[3];
  const float* Wo = (const float*)d_in[4];
  const float* W1 = (const float*)d_in[5];
  const float* b1 = (const float*)d_in[6];
  const float* W2 = (const float*)d_in[7];
  const float* b2 = (const float*)d_in[8];
  const float* g1 = (const float*)d_in[9];
  const float* be1 = (const float*)d_in[10];
  const float* g2 = (const float*)d_in[11];
  const float* be2 = (const float*)d_in[12];

  char* ws = (char*)d_ws;
  const size_t MB = 1u << 20;
  u16*   x_bf    = (u16*)(ws + 0 * MB);     // 8MB [4096][1024]
  u16*   WqkvT   = (u16*)(ws + 8 * MB);     // 6MB [3072][1024]
  u16*   WoB     = (u16*)(ws + 14 * MB);    // 2MB [1024][1024] (n,k)
  u16*   W1T     = (u16*)(ws + 16 * MB);    // 8MB [4096][1024]
  u16*   W2T     = (u16*)(ws + 24 * MB);    // 8MB [1024][4096]
  u16*   q_bf    = (u16*)(ws + 32 * MB);    // 8MB [B,H,T,64]  (qkv contiguous)
  u16*   v_bf    = (u16*)(ws + 48 * MB);    // 8MB [B,H,T,64]
  u16*   vT_bf   = (u16*)(ws + 56 * MB);    // 8MB [B,H,64,T]
  u16*   ctx_bf  = (u16*)(ws + 64 * MB);    // 8MB [B,T,H,64]
  u16*   attn_bf = (u16*)(ws + 72 * MB);    // 8MB [4096][1024]
  float* h       = (float*)(ws + 80 * MB);  // 16MB fp32
  u16*   h_bf    = (u16*)(ws + 0 * MB);     // reuse x_bf (dead after QKV)
  u16*   ffn1_bf = (u16*)(ws + 32 * MB);    // 32MB reuse q/k/v/vT
  u16*   ffn2_bf = (u16*)(ws + 8 * MB);     // 8MB reuse WqkvT

  const dim3 blk(256);
  const float lg2e = 1.44269504f;

  conv_f2b<<<NTOK, blk, 0, stream>>>(x, x_bf, NTOK * D_MODEL);
  // fold 1/sqrt(dk) * log2(e) into Wq so QK scores land in exp2 domain
  transpose_f2b<<<dim3(16, 16), blk, 0, stream>>>(Wq, WqkvT, D_MODEL, D_MODEL,
                                                  0.125f * lg2e);
  transpose_f2b<<<dim3(16, 16), blk, 0, stream>>>(Wk, WqkvT + 1024 * 1024,
                                                  D_MODEL, D_MODEL, 1.f);
  transpose_f2b<<<dim3(16, 16), blk, 0, stream>>>(Wv, WqkvT + 2 * 1024 * 1024,
                                                  D_MODEL, D_MODEL, 1.f);
  conv_f2b<<<1024, blk, 0, stream>>>(Wo, WoB, D_MODEL * D_MODEL);
  transpose_f2b<<<dim3(64, 16), blk, 0, stream>>>(W1, W1T, D_MODEL, FF_DIM, 1.f);
  transpose_f2b<<<dim3(16, 64), blk, 0, stream>>>(W2, W2T, FF_DIM, D_MODEL, 1.f);

  // merged QKV projection: [4096,1024] x [3072,1024]^T -> scatter q/k/v
  gemm_mfma<2, false, false><<<dim3(24, 32), blk, 0, stream>>>(
      x_bf, WqkvT, nullptr, q_bf, NTOK, 3072, D_MODEL, 1.f);

  transpose_v<<<dim3(32, 32), blk, 0, stream>>>(v_bf, vT_bf);

  attn_mfma<<<dim3(T_SEQ / 128, 32), blk, 0, stream>>>(q_bf, q_bf + 4194304,
                                                       vT_bf, ctx_bf);

  gemm_mfma<1, false, false><<<dim3(8, 32), blk, 0, stream>>>(
      ctx_bf, WoB, nullptr, attn_bf, NTOK, D_MODEL, D_MODEL, 1.f);

  add_layernorm<true><<<NTOK, blk, 0, stream>>>(x, attn_bf, g1, be1, h, h_bf);

  gemm_mfma<1, true, true><<<dim3(32, 32), blk, 0, stream>>>(
      h_bf, W1T, b1, ffn1_bf, NTOK, FF_DIM, D_MODEL, 1.f);
  gemm_mfma<1, true, false><<<dim3(8, 32), blk, 0, stream>>>(
      ffn1_bf, W2T, b2, ffn2_bf, NTOK, D_MODEL, FF_DIM, 1.f);

  add_layernorm<false><<<NTOK, blk, 0, stream>>>(h, ffn2_bf, g2, be2,
                                                 (float*)d_out, nullptr);
}

// Round 6
// 386.129 us; speedup vs baseline: 10.5397x; 1.0395x over previous
//
#include <hip/hip_runtime.h>
#include <math.h>

#define T_SEQ 2048
#define D_MODEL 1024
#define NHEAD 16
#define DHEAD 64
#define FF_DIM 4096
#define NTOK 4096   // B*T
#define LN_EPS 1e-6f

typedef unsigned short u16;
typedef unsigned int u32;
typedef __attribute__((ext_vector_type(8))) __bf16 bf16x8;
typedef __attribute__((ext_vector_type(4))) float f32x4;
typedef __attribute__((ext_vector_type(16))) float f32x16;

typedef const void __attribute__((address_space(1))) gvoid;
typedef void __attribute__((address_space(3))) lvoid;

__device__ __forceinline__ u16 f2bf(float f) {
  unsigned u = __float_as_uint(f);
  return (u16)((u + 0x7fffu + ((u >> 16) & 1u)) >> 16);
}
__device__ __forceinline__ float bf2f(u16 u) {
  return __uint_as_float((unsigned)u << 16);
}
// v_cvt_pk_bf16_f32: pack 2 f32 -> 2 bf16 in one dword (lo, hi)
__device__ __forceinline__ u32 cvtpk(float lo, float hi) {
  u32 r;
  asm("v_cvt_pk_bf16_f32 %0, %1, %2" : "=v"(r) : "v"(lo), "v"(hi));
  return r;
}

// async global(16B/lane) -> LDS; dest = wave-uniform base + lane*16B
__device__ __forceinline__ void gll16(const u16* g, u16* l) {
  __builtin_amdgcn_global_load_lds((gvoid*)g, (lvoid*)l, 16, 0, 0);
}

// read one 16B fragment from a [rows][64] bf16 LDS tile with chunk-XOR swizzle
__device__ __forceinline__ bf16x8 lds_frag(const u16* lds, int row, int chunk) {
  return *(const bf16x8*)&lds[row * 64 + ((chunk ^ (row & 7)) * 8)];
}

union BF8 { u32 u[4]; bf16x8 v; };

// ---------------------------------------------------------------------------
// fp32 -> bf16 flat convert (n % 1024 == 0)
// ---------------------------------------------------------------------------
__global__ __launch_bounds__(256) void conv_f2b(const float* __restrict__ in,
                                                u16* __restrict__ out, int n) {
  const int i = (blockIdx.x * 256 + threadIdx.x) * 4;
  if (i >= n) return;
  const float4 v = *(const float4*)&in[i];
  ushort4 o;
  o.x = f2bf(v.x); o.y = f2bf(v.y); o.z = f2bf(v.z); o.w = f2bf(v.w);
  *(ushort4*)&out[i] = o;
}

// ---------------------------------------------------------------------------
// fp32 [K,N] -> bf16 [N,K] transpose (optional scale). 64x64 tiles.
// ---------------------------------------------------------------------------
__global__ __launch_bounds__(256) void transpose_f2b(
    const float* __restrict__ in, u16* __restrict__ out, int K, int N,
    float scale) {
  __shared__ u16 t[64][72];
  const int tid = threadIdx.x;
  const int k0 = blockIdx.y * 64, n0 = blockIdx.x * 64;
  const int nl = tid & 63;
#pragma unroll
  for (int i = 0; i < 16; ++i) {
    const int kl = (tid >> 6) * 16 + i;
    t[nl][kl] = f2bf(in[(size_t)(k0 + kl) * N + n0 + nl] * scale);
  }
  __syncthreads();
  const int nr = tid >> 2, kc = (tid & 3) * 16;
  const uint4 a = *(const uint4*)&t[nr][kc];
  const uint4 b = *(const uint4*)&t[nr][kc + 8];
  *(uint4*)&out[(size_t)(n0 + nr) * K + k0 + kc] = a;
  *(uint4*)&out[(size_t)(n0 + nr) * K + k0 + kc + 8] = b;
}

// ---------------------------------------------------------------------------
// bf16 [B,H,T,64] -> bf16 [B,H,64,T]. grid (T/64, B*H)
// ---------------------------------------------------------------------------
__global__ __launch_bounds__(256) void transpose_v(const u16* __restrict__ vin,
                                                   u16* __restrict__ vout) {
  __shared__ u16 t[64][72];
  const int tid = threadIdx.x;
  const int bh = blockIdx.y;
  const int t0 = blockIdx.x * 64;
  const u16* src = vin + ((size_t)bh * T_SEQ + t0) * 64;
#pragma unroll
  for (int i = 0; i < 2; ++i) {
    const int r = i * 32 + (tid >> 3);
    const int ch = tid & 7;
    *(uint4*)&t[r][ch * 8] = *(const uint4*)&src[(size_t)r * 64 + ch * 8];
  }
  __syncthreads();
  const int d = tid >> 2, p = (tid & 3) * 16;
  alignas(16) u16 tmp[16];
#pragma unroll
  for (int i = 0; i < 16; ++i) tmp[i] = t[p + i][d];
  u16* dst = vout + ((size_t)bh * 64 + d) * T_SEQ + t0 + p;
  *(uint4*)&dst[0] = *(const uint4*)&tmp[0];
  *(uint4*)&dst[8] = *(const uint4*)&tmp[8];
}

// ---------------------------------------------------------------------------
// bf16 MFMA GEMM, 2-phase pipelined, XCD-swizzled, optional split-K (grid.z).
// C[m,n] = scale*sum_k A[m,k]*BT[n,k] (+bias)(relu)
// OUTMODE: 1 = bf16 [M,N] (split-K half z at C + z*M*N)
//          2 = qkv scatter: col<1024->q, <2048->k, else v, regions of 4M elts.
// (gridDim.x*gridDim.y) % 8 == 0 required.
// ---------------------------------------------------------------------------
template <int OUTMODE, bool BIAS, bool RELU, int SPLITK>
__global__ __launch_bounds__(256) void gemm_mfma(
    const u16* __restrict__ A, const u16* __restrict__ BT,
    const float* __restrict__ bias, void* __restrict__ C,
    int M, int N, int K, float scale) {
  __shared__ u16 smem[16384];  // [buf:2][A|B][128*32]

  const int tid = threadIdx.x;
  const int w = tid >> 6, lane = tid & 63;

  const int nwg = gridDim.x * gridDim.y;
  int bid = blockIdx.y * gridDim.x + blockIdx.x;
  const int cpx = nwg >> 3;
  bid = (bid & 7) * cpx + (bid >> 3);  // XCD-contiguous chunks
  const int bx = bid % gridDim.x, by = bid / gridDim.x;
  const int m0 = by * 128, n0 = bx * 128;
  const int wr = (w >> 1) * 64, wc = (w & 1) * 64;

  const int kpb = K / SPLITK;
  const int kbase = blockIdx.z * kpb;

  f32x4 acc[4][4];
#pragma unroll
  for (int i = 0; i < 4; ++i)
#pragma unroll
    for (int j = 0; j < 4; ++j) acc[i][j] = (f32x4)0.f;

  const int srow = w * 32 + (lane >> 2);
  const int scol = (lane & 3) * 8;
  const u16* gA0 = A + (size_t)(m0 + srow) * K + kbase + scol;
  const u16* gA1 = gA0 + (size_t)16 * K;
  const u16* gB0 = BT + (size_t)(n0 + srow) * K + kbase + scol;
  const u16* gB1 = gB0 + (size_t)16 * K;

  const int arow = lane & 15;
  const int koff = (lane >> 4) * 8;

  auto stage = [&](int buf, int k0) {
    u16* base = smem + buf * 8192;
    gll16(gA0 + k0, base + w * 1024);
    gll16(gA1 + k0, base + w * 1024 + 512);
    gll16(gB0 + k0, base + 4096 + w * 1024);
    gll16(gB1 + k0, base + 4096 + w * 1024 + 512);
  };

  stage(0, 0);
  __syncthreads();

  const int nk = kpb >> 5;
  for (int it = 0; it < nk; ++it) {
    const int buf = it & 1;
    if (it + 1 < nk) stage(buf ^ 1, (it + 1) << 5);

    const u16* sb = smem + buf * 8192;
    bf16x8 af[4], bff[4];
#pragma unroll
    for (int m = 0; m < 4; ++m)
      af[m] = *(const bf16x8*)&sb[(wr + m * 16 + arow) * 32 + koff];
#pragma unroll
    for (int n = 0; n < 4; ++n)
      bff[n] = *(const bf16x8*)&sb[4096 + (wc + n * 16 + arow) * 32 + koff];
#pragma unroll
    for (int m = 0; m < 4; ++m)
#pragma unroll
      for (int n = 0; n < 4; ++n)
        acc[m][n] = __builtin_amdgcn_mfma_f32_16x16x32_bf16(
            af[m], bff[n], acc[m][n], 0, 0, 0);
    __syncthreads();
  }

  // epilogue: D layout col=lane&15, row=(lane>>4)*4+reg  [m89-verified]
  u16* Cb = (u16*)C;
  if (SPLITK > 1) Cb += (size_t)blockIdx.z * M * N;
  const int rbase = (lane >> 4) * 4;
  const int cl = lane & 15;
#pragma unroll
  for (int n = 0; n < 4; ++n) {
    const int col = n0 + wc + n * 16 + cl;
    const float bia = BIAS ? bias[col] : 0.f;
#pragma unroll
    for (int m = 0; m < 4; ++m) {
      const int row0 = m0 + wr + m * 16 + rbase;
#pragma unroll
      for (int r = 0; r < 4; ++r) {
        float vv = acc[m][n][r] * scale + bia;
        if (RELU) vv = fmaxf(vv, 0.f);
        const int row = row0 + r;
        if (OUTMODE == 1) {
          Cb[(size_t)row * N + col] = f2bf(vv);
        } else {
          const int reg = col >> 10, cl2 = col & 1023;
          const size_t off =
              (size_t)reg * 4194304 +
              ((size_t)((row >> 11) * NHEAD + (cl2 >> 6)) * T_SEQ +
               (row & 2047)) * 64 + (cl2 & 63);
          Cb[off] = f2bf(vv);
        }
      }
    }
  }
}

// ---------------------------------------------------------------------------
// MFMA causal flash attention, swapped-operand, QBLK=64, 2 waves/block.
// q,k: [B,H,T,64] bf16 (q pre-scaled by 0.125*log2e). vT: [B,H,64,T] bf16.
// ctx out: [B,T,H,64] bf16. Grid: (T/64, B*H), 128 thr; wave = 32 q rows.
// QK^T = mfma(K, Q) -> S^T[s][q]; PV = mfma(V^T, P^T) -> O^T[d][q].
// ---------------------------------------------------------------------------
__global__ __launch_bounds__(128) void attn_mfma(
    const u16* __restrict__ qg, const u16* __restrict__ kg,
    const u16* __restrict__ vtg, u16* __restrict__ ctx) {
  __shared__ u16 Ks[2][64 * 64];
  __shared__ u16 Vs[2][64 * 64];

  const int tid = threadIdx.x;
  const int w = tid >> 6, lane = tid & 63;
  const int qt = gridDim.x - 1 - blockIdx.x;  // big blocks first
  const int bh = blockIdx.y;
  const int l31 = lane & 31, hi32 = lane >> 5;
  const int r8 = lane >> 3, cswz = (lane & 7) ^ r8;

  const u16* qhead = qg + (size_t)bh * (T_SEQ * 64);
  const u16* khead = kg + (size_t)bh * (T_SEQ * 64);
  const u16* vhead = vtg + (size_t)bh * (64 * T_SEQ);

  const int qbase = qt * 64;
  const int qrow = qbase + w * 32 + l31;  // this lane's q row (global t)

  // Q B-fragments (col=l31, k = ks2*16 + hi32*8 + i), resident all kernel
  bf16x8 qb[4];
#pragma unroll
  for (int ks2 = 0; ks2 < 4; ++ks2)
    qb[ks2] = *(const bf16x8*)&qhead[(size_t)qrow * 64 + ks2 * 16 + hi32 * 8];

  f32x16 o0 = (f32x16)0.f, o1 = (f32x16)0.f;  // O^T: d = dv*32 + rowmap
  float m = -INFINITY, l = 0.f;

  const int nt = qt + 1;

  // each of 2 waves stages 32 K rows + 32 V^T rows per tile
  auto stage = [&](int buf, int s0) {
#pragma unroll
    for (int i = 0; i < 4; ++i) {
      const int row = w * 32 + i * 8 + r8;
      gll16(khead + (size_t)(s0 + row) * 64 + cswz * 8,
            &Ks[buf][(w * 32 + i * 8) * 64]);
      gll16(vhead + (size_t)row * T_SEQ + s0 + cswz * 8,
            &Vs[buf][(w * 32 + i * 8) * 64]);
    }
  };

  stage(0, 0);
  __syncthreads();

  for (int it = 0; it < nt; ++it) {
    const int buf = it & 1;
    if (it + 1 < nt) stage(buf ^ 1, (it + 1) * 64);

    // ---- QK^T: S^T[s=sub*32+rowmap][q=l31], 8 MFMA 32x32x16
    f32x16 st0 = (f32x16)0.f, st1 = (f32x16)0.f;
    __builtin_amdgcn_s_setprio(1);
#pragma unroll
    for (int ks2 = 0; ks2 < 4; ++ks2) {
      const bf16x8 kf0 = lds_frag(Ks[buf], l31, ks2 * 2 + hi32);
      st0 = __builtin_amdgcn_mfma_f32_32x32x16_bf16(kf0, qb[ks2], st0, 0, 0, 0);
    }
#pragma unroll
    for (int ks2 = 0; ks2 < 4; ++ks2) {
      const bf16x8 kf1 = lds_frag(Ks[buf], 32 + l31, ks2 * 2 + hi32);
      st1 = __builtin_amdgcn_mfma_f32_32x32x16_bf16(kf1, qb[ks2], st1, 0, 0, 0);
    }
    __builtin_amdgcn_s_setprio(0);

    // ---- causal mask (diagonal = last tile)
    if (it == nt - 1) {
      const int s0g = it * 64;
#pragma unroll
      for (int r = 0; r < 16; ++r) {
        const int rowm = (r & 3) + 8 * (r >> 2) + 4 * hi32;
        if (s0g + rowm > qrow) st0[r] = -1e30f;
        if (s0g + 32 + rowm > qrow) st1[r] = -1e30f;
      }
    }

    // ---- online softmax (exp2 domain): s-axis lane-local + 1 swap
    float mx = fmaxf(st0[0], st1[0]);
#pragma unroll
    for (int r = 1; r < 16; ++r) mx = fmaxf(mx, fmaxf(st0[r], st1[r]));
    mx = fmaxf(mx, __shfl_xor(mx, 32));

    float corr = 1.f;
    if (!__all(mx <= m + 11.5f)) {  // defer-max (T13)
      const float mn = fmaxf(m, mx);
      corr = exp2f(m - mn);
      m = mn;
#pragma unroll
      for (int r = 0; r < 16; ++r) { o0[r] *= corr; o1[r] *= corr; }
    }
    float ps = 0.f;
#pragma unroll
    for (int r = 0; r < 16; ++r) {
      st0[r] = exp2f(st0[r] - m);
      st1[r] = exp2f(st1[r] - m);
      ps += st0[r] + st1[r];
    }
    ps += __shfl_xor(ps, 32);
    l = l * corr + ps;

    // ---- P^T B-fragments in-register: cvt_pk + permlane32_swap (T12)
    BF8 pb[4];
#pragma unroll
    for (int blk = 0; blk < 2; ++blk) {
      {
        u32 x0 = cvtpk(st0[blk * 8 + 0], st0[blk * 8 + 1]);
        u32 x1 = cvtpk(st0[blk * 8 + 2], st0[blk * 8 + 3]);
        u32 y0 = cvtpk(st0[blk * 8 + 4], st0[blk * 8 + 5]);
        u32 y1 = cvtpk(st0[blk * 8 + 6], st0[blk * 8 + 7]);
        asm("v_permlane32_swap_b32 %0, %1" : "+v"(x0), "+v"(y0));
        asm("v_permlane32_swap_b32 %0, %1" : "+v"(x1), "+v"(y1));
        pb[blk].u[0] = x0; pb[blk].u[1] = x1;
        pb[blk].u[2] = y0; pb[blk].u[3] = y1;
      }
      {
        u32 x0 = cvtpk(st1[blk * 8 + 0], st1[blk * 8 + 1]);
        u32 x1 = cvtpk(st1[blk * 8 + 2], st1[blk * 8 + 3]);
        u32 y0 = cvtpk(st1[blk * 8 + 4], st1[blk * 8 + 5]);
        u32 y1 = cvtpk(st1[blk * 8 + 6], st1[blk * 8 + 7]);
        asm("v_permlane32_swap_b32 %0, %1" : "+v"(x0), "+v"(y0));
        asm("v_permlane32_swap_b32 %0, %1" : "+v"(x1), "+v"(y1));
        pb[2 + blk].u[0] = x0; pb[2 + blk].u[1] = x1;
        pb[2 + blk].u[2] = y0; pb[2 + blk].u[3] = y1;
      }
    }

    // ---- PV: O^T[d][q] += V^T[d][s] * P^T[s][q], 8 MFMA
    __builtin_amdgcn_s_setprio(1);
#pragma unroll
    for (int ks = 0; ks < 4; ++ks) {
      const bf16x8 vf0 = lds_frag(Vs[buf], l31, ks * 2 + hi32);
      o0 = __builtin_amdgcn_mfma_f32_32x32x16_bf16(vf0, pb[ks].v, o0, 0, 0, 0);
    }
#pragma unroll
    for (int ks = 0; ks < 4; ++ks) {
      const bf16x8 vf1 = lds_frag(Vs[buf], 32 + l31, ks * 2 + hi32);
      o1 = __builtin_amdgcn_mfma_f32_32x32x16_bf16(vf1, pb[ks].v, o1, 0, 0, 0);
    }
    __builtin_amdgcn_s_setprio(0);
    __syncthreads();
  }

  // ---- epilogue: normalize, transpose O^T->O via per-wave LDS, store ctx
  const float inv = 1.0f / l;
#pragma unroll
  for (int r = 0; r < 16; ++r) { o0[r] *= inv; o1[r] *= inv; }

  u16* ep = &Ks[0][0] + w * 2048;  // per-wave 32q x 64d bf16, chunk-swizzled
#pragma unroll
  for (int rg = 0; rg < 4; ++rg) {
    const u32 w0 = cvtpk(o0[rg * 4 + 0], o0[rg * 4 + 1]);
    const u32 w1 = cvtpk(o0[rg * 4 + 2], o0[rg * 4 + 3]);
    uint2 val; val.x = w0; val.y = w1;
    *(uint2*)&ep[l31 * 64 + ((rg ^ (l31 & 7)) * 8) + hi32 * 4] = val;
  }
#pragma unroll
  for (int rg = 0; rg < 4; ++rg) {
    const u32 w0 = cvtpk(o1[rg * 4 + 0], o1[rg * 4 + 1]);
    const u32 w1 = cvtpk(o1[rg * 4 + 2], o1[rg * 4 + 3]);
    const int chunk = 4 + rg;
    uint2 val; val.x = w0; val.y = w1;
    *(uint2*)&ep[l31 * 64 + ((chunk ^ (l31 & 7)) * 8) + hi32 * 4] = val;
  }

  const int b = bh >> 4, h = bh & 15;
  const int ql = lane >> 1, half = lane & 1;
  const int t = qbase + w * 32 + ql;
  u16* dst = ctx + ((size_t)(b * T_SEQ + t) * NHEAD + h) * 64;
#pragma unroll
  for (int j = 0; j < 4; ++j) {
    const int chunk = half * 4 + j;
    const uint4 vv = *(const uint4*)&ep[ql * 64 + ((chunk ^ (ql & 7)) * 8)];
    *(uint4*)&dst[chunk * 8] = vv;
  }
}

// ---------------------------------------------------------------------------
// out = LayerNorm(x + y0 [+ y1] [+ bias]) * g + be over last dim 1024.
// y0,y1 bf16 (y1 nullable), bias fp32 nullable (per-column).
// ---------------------------------------------------------------------------
template <bool EMIT_BF>
__global__ __launch_bounds__(256) void add_layernorm(
    const float* __restrict__ x, const u16* __restrict__ y0,
    const u16* __restrict__ y1, const float* __restrict__ bias,
    const float* __restrict__ g, const float* __restrict__ be,
    float* __restrict__ out, u16* __restrict__ out_bf) {
  const int row = blockIdx.x;
  const int tid = threadIdx.x;
  const size_t base = (size_t)row * D_MODEL + tid * 4;

  const float4 xv = *(const float4*)&x[base];
  const ushort4 y0v = *(const ushort4*)&y0[base];
  float v0 = xv.x + bf2f(y0v.x), v1 = xv.y + bf2f(y0v.y);
  float v2 = xv.z + bf2f(y0v.z), v3 = xv.w + bf2f(y0v.w);
  if (y1) {
    const ushort4 y1v = *(const ushort4*)&y1[base];
    v0 += bf2f(y1v.x); v1 += bf2f(y1v.y);
    v2 += bf2f(y1v.z); v3 += bf2f(y1v.w);
  }
  if (bias) {
    const float4 bv = *(const float4*)&bias[tid * 4];
    v0 += bv.x; v1 += bv.y; v2 += bv.z; v3 += bv.w;
  }

  float s = v0 + v1 + v2 + v3;
  float ss = v0 * v0 + v1 * v1 + v2 * v2 + v3 * v3;
#pragma unroll
  for (int off = 32; off > 0; off >>= 1) {
    s += __shfl_down(s, off);
    ss += __shfl_down(ss, off);
  }
  __shared__ float red[8];
  const int wid = tid >> 6, lane = tid & 63;
  if (lane == 0) { red[wid] = s; red[4 + wid] = ss; }
  __syncthreads();
  s = red[0] + red[1] + red[2] + red[3];
  ss = red[4] + red[5] + red[6] + red[7];

  const float mean = s * (1.0f / D_MODEL);
  const float var = ss * (1.0f / D_MODEL) - mean * mean;
  const float rr = rsqrtf(var + LN_EPS);

  const float4 g4 = *(const float4*)&g[tid * 4];
  const float4 b4 = *(const float4*)&be[tid * 4];
  float4 o4;
  o4.x = (v0 - mean) * rr * g4.x + b4.x;
  o4.y = (v1 - mean) * rr * g4.y + b4.y;
  o4.z = (v2 - mean) * rr * g4.z + b4.z;
  o4.w = (v3 - mean) * rr * g4.w + b4.w;
  *(float4*)&out[base] = o4;
  if (EMIT_BF) {
    ushort4 ob;
    ob.x = f2bf(o4.x); ob.y = f2bf(o4.y); ob.z = f2bf(o4.z); ob.w = f2bf(o4.w);
    *(ushort4*)&out_bf[base] = ob;
  }
}

// ---------------------------------------------------------------------------
extern "C" void kernel_launch(void* const* d_in, const int* in_sizes, int n_in,
                              void* d_out, int out_size, void* d_ws,
                              size_t ws_size, hipStream_t stream) {
  const float* x  = (const float*)d_in[0];
  const float* Wq = (const float*)d_in[1];
  const float* Wk = (const float*)d_in[2];
  const float* Wv = (const float*)d_in[3];
  const float* Wo = (const float*)d_in[4];
  const float* W1 = (const float*)d_in[5];
  const float* b1 = (const float*)d_in[6];
  const float* W2 = (const float*)d_in[7];
  const float* b2 = (const float*)d_in[8];
  const float* g1 = (const float*)d_in[9];
  const float* be1 = (const float*)d_in[10];
  const float* g2 = (const float*)d_in[11];
  const float* be2 = (const float*)d_in[12];

  char* ws = (char*)d_ws;
  const size_t MB = 1u << 20;
  u16*   x_bf    = (u16*)(ws + 0 * MB);     // 8MB [4096][1024]
  u16*   WqkvT   = (u16*)(ws + 8 * MB);     // 6MB [3072][1024]
  u16*   WoB     = (u16*)(ws + 14 * MB);    // 2MB [1024][1024] (n,k)
  u16*   W1T     = (u16*)(ws + 16 * MB);    // 8MB [4096][1024]
  u16*   W2T     = (u16*)(ws + 24 * MB);    // 8MB [1024][4096]
  u16*   q_bf    = (u16*)(ws + 32 * MB);    // 8MB [B,H,T,64] (qkv contiguous)
  u16*   v_bf    = (u16*)(ws + 48 * MB);    // 8MB [B,H,T,64]
  u16*   vT_bf   = (u16*)(ws + 56 * MB);    // 8MB [B,H,64,T]
  u16*   ctx_bf  = (u16*)(ws + 64 * MB);    // 8MB [B,T,H,64]
  u16*   attn01  = (u16*)(ws + 32 * MB);    // 16MB: Wo split-K halves (q/k dead)
  float* h       = (float*)(ws + 80 * MB);  // 16MB fp32
  u16*   h_bf    = (u16*)(ws + 0 * MB);     // reuse x_bf (dead after QKV)
  u16*   ffn1_bf = (u16*)(ws + 32 * MB);    // 32MB reuse attn01/v/vT after LN1
  u16*   ffn2_01 = (u16*)(ws + 64 * MB);    // 16MB: FFN2 split halves (ctx dead)

  const dim3 blk(256);
  const float lg2e = 1.44269504f;

  conv_f2b<<<NTOK, blk, 0, stream>>>(x, x_bf, NTOK * D_MODEL);
  // fold 1/sqrt(dk) * log2(e) into Wq so QK scores land in exp2 domain
  transpose_f2b<<<dim3(16, 16), blk, 0, stream>>>(Wq, WqkvT, D_MODEL, D_MODEL,
                                                  0.125f * lg2e);
  transpose_f2b<<<dim3(16, 16), blk, 0, stream>>>(Wk, WqkvT + 1024 * 1024,
                                                  D_MODEL, D_MODEL, 1.f);
  transpose_f2b<<<dim3(16, 16), blk, 0, stream>>>(Wv, WqkvT + 2 * 1024 * 1024,
                                                  D_MODEL, D_MODEL, 1.f);
  conv_f2b<<<1024, blk, 0, stream>>>(Wo, WoB, D_MODEL * D_MODEL);
  transpose_f2b<<<dim3(64, 16), blk, 0, stream>>>(W1, W1T, D_MODEL, FF_DIM, 1.f);
  transpose_f2b<<<dim3(16, 64), blk, 0, stream>>>(W2, W2T, FF_DIM, D_MODEL, 1.f);

  // merged QKV projection: [4096,1024] x [3072,1024]^T -> scatter q/k/v
  gemm_mfma<2, false, false, 1><<<dim3(24, 32), blk, 0, stream>>>(
      x_bf, WqkvT, nullptr, q_bf, NTOK, 3072, D_MODEL, 1.f);

  transpose_v<<<dim3(32, 32), blk, 0, stream>>>(v_bf, vT_bf);

  attn_mfma<<<dim3(T_SEQ / 64, 32), dim3(128), 0, stream>>>(
      q_bf, q_bf + 4194304, vT_bf, ctx_bf);

  // output projection, split-K=2 -> two bf16 halves summed in LN1
  gemm_mfma<1, false, false, 2><<<dim3(8, 32, 2), blk, 0, stream>>>(
      ctx_bf, WoB, nullptr, attn01, NTOK, D_MODEL, D_MODEL, 1.f);

  add_layernorm<true><<<NTOK, blk, 0, stream>>>(
      x, attn01, attn01 + 4194304, nullptr, g1, be1, h, h_bf);

  gemm_mfma<1, true, true, 1><<<dim3(32, 32), blk, 0, stream>>>(
      h_bf, W1T, b1, ffn1_bf, NTOK, FF_DIM, D_MODEL, 1.f);

  // FFN2, split-K=2 -> two bf16 halves; b2 folded into LN2
  gemm_mfma<1, false, false, 2><<<dim3(8, 32, 2), blk, 0, stream>>>(
      ffn1_bf, W2T, nullptr, ffn2_01, NTOK, D_MODEL, FF_DIM, 1.f);

  add_layernorm<false><<<NTOK, blk, 0, stream>>>(
      h, ffn2_01, ffn2_01 + 4194304, b2, g2, be2, (float*)d_out, nullptr);
}

// Round 7
// 381.245 us; speedup vs baseline: 10.6747x; 1.0128x over previous
//
#include <hip/hip_runtime.h>
#include <math.h>

#define T_SEQ 2048
#define D_MODEL 1024
#define NHEAD 16
#define DHEAD 64
#define FF_DIM 4096
#define NTOK 4096   // B*T
#define LN_EPS 1e-6f

typedef unsigned short u16;
typedef unsigned int u32;
typedef __attribute__((ext_vector_type(8))) __bf16 bf16x8;
typedef __attribute__((ext_vector_type(4))) float f32x4;
typedef __attribute__((ext_vector_type(16))) float f32x16;

typedef const void __attribute__((address_space(1))) gvoid;
typedef void __attribute__((address_space(3))) lvoid;

__device__ __forceinline__ u16 f2bf(float f) {
  unsigned u = __float_as_uint(f);
  return (u16)((u + 0x7fffu + ((u >> 16) & 1u)) >> 16);
}
__device__ __forceinline__ float bf2f(u16 u) {
  return __uint_as_float((unsigned)u << 16);
}
// v_cvt_pk_bf16_f32: pack 2 f32 -> 2 bf16 in one dword (lo, hi)
__device__ __forceinline__ u32 cvtpk(float lo, float hi) {
  u32 r;
  asm("v_cvt_pk_bf16_f32 %0, %1, %2" : "=v"(r) : "v"(lo), "v"(hi));
  return r;
}

// async global(16B/lane) -> LDS; dest = wave-uniform base + lane*16B
__device__ __forceinline__ void gll16(const u16* g, u16* l) {
  __builtin_amdgcn_global_load_lds((gvoid*)g, (lvoid*)l, 16, 0, 0);
}

// counted-vmcnt barrier pair (T4): only tile-t loads drained, t+1 stays in flight
#define WAIT_VM_BARRIER(N) \
  asm volatile("s_waitcnt vmcnt(" #N ")\n\ts_barrier" ::: "memory")
#define LGKM_BARRIER() \
  asm volatile("s_waitcnt lgkmcnt(0)\n\ts_barrier" ::: "memory")

// read one 16B fragment from a [rows][64] bf16 LDS tile with chunk-XOR swizzle
__device__ __forceinline__ bf16x8 lds_frag(const u16* lds, int row, int chunk) {
  return *(const bf16x8*)&lds[row * 64 + ((chunk ^ (row & 7)) * 8)];
}

union BF8 { u32 u[4]; bf16x8 v; };

// ---------------------------------------------------------------------------
// fp32 -> bf16 flat convert (n % 1024 == 0)
// ---------------------------------------------------------------------------
__global__ __launch_bounds__(256) void conv_f2b(const float* __restrict__ in,
                                                u16* __restrict__ out, int n) {
  const int i = (blockIdx.x * 256 + threadIdx.x) * 4;
  if (i >= n) return;
  const float4 v = *(const float4*)&in[i];
  ushort4 o;
  o.x = f2bf(v.x); o.y = f2bf(v.y); o.z = f2bf(v.z); o.w = f2bf(v.w);
  *(ushort4*)&out[i] = o;
}

// ---------------------------------------------------------------------------
// fp32 [K,N] -> bf16 [N,K] transpose (optional scale). 64x64 tiles.
// ---------------------------------------------------------------------------
__global__ __launch_bounds__(256) void transpose_f2b(
    const float* __restrict__ in, u16* __restrict__ out, int K, int N,
    float scale) {
  __shared__ u16 t[64][72];
  const int tid = threadIdx.x;
  const int k0 = blockIdx.y * 64, n0 = blockIdx.x * 64;
  const int nl = tid & 63;
#pragma unroll
  for (int i = 0; i < 16; ++i) {
    const int kl = (tid >> 6) * 16 + i;
    t[nl][kl] = f2bf(in[(size_t)(k0 + kl) * N + n0 + nl] * scale);
  }
  __syncthreads();
  const int nr = tid >> 2, kc = (tid & 3) * 16;
  const uint4 a = *(const uint4*)&t[nr][kc];
  const uint4 b = *(const uint4*)&t[nr][kc + 8];
  *(uint4*)&out[(size_t)(n0 + nr) * K + k0 + kc] = a;
  *(uint4*)&out[(size_t)(n0 + nr) * K + k0 + kc + 8] = b;
}

// ---------------------------------------------------------------------------
// bf16 [B,H,T,64] -> bf16 [B,H,64,T]. grid (T/64, B*H)
// ---------------------------------------------------------------------------
__global__ __launch_bounds__(256) void transpose_v(const u16* __restrict__ vin,
                                                   u16* __restrict__ vout) {
  __shared__ u16 t[64][72];
  const int tid = threadIdx.x;
  const int bh = blockIdx.y;
  const int t0 = blockIdx.x * 64;
  const u16* src = vin + ((size_t)bh * T_SEQ + t0) * 64;
#pragma unroll
  for (int i = 0; i < 2; ++i) {
    const int r = i * 32 + (tid >> 3);
    const int ch = tid & 7;
    *(uint4*)&t[r][ch * 8] = *(const uint4*)&src[(size_t)r * 64 + ch * 8];
  }
  __syncthreads();
  const int d = tid >> 2, p = (tid & 3) * 16;
  alignas(16) u16 tmp[16];
#pragma unroll
  for (int i = 0; i < 16; ++i) tmp[i] = t[p + i][d];
  u16* dst = vout + ((size_t)bh * 64 + d) * T_SEQ + t0 + p;
  *(uint4*)&dst[0] = *(const uint4*)&tmp[0];
  *(uint4*)&dst[8] = *(const uint4*)&tmp[8];
}

// ---------------------------------------------------------------------------
// bf16 MFMA GEMM, counted-vmcnt pipelined, XCD-swizzled, optional split-K.
// C[m,n] = scale*sum_k A[m,k]*BT[n,k] (+bias)(relu)
// OUTMODE: 1 = bf16 [M,N] (split-K half z at C + z*M*N)
//          2 = qkv scatter: col<1024->q, <2048->k, else v, regions of 4M elts.
// (gridDim.x*gridDim.y) % 8 == 0 required.
// ---------------------------------------------------------------------------
template <int OUTMODE, bool BIAS, bool RELU, int SPLITK>
__global__ __launch_bounds__(256) void gemm_mfma(
    const u16* __restrict__ A, const u16* __restrict__ BT,
    const float* __restrict__ bias, void* __restrict__ C,
    int M, int N, int K, float scale) {
  __shared__ u16 smem[16384];  // [buf:2][A|B][128*32]

  const int tid = threadIdx.x;
  const int w = tid >> 6, lane = tid & 63;

  const int nwg = gridDim.x * gridDim.y;
  int bid = blockIdx.y * gridDim.x + blockIdx.x;
  const int cpx = nwg >> 3;
  bid = (bid & 7) * cpx + (bid >> 3);  // XCD-contiguous chunks
  const int bx = bid % gridDim.x, by = bid / gridDim.x;
  const int m0 = by * 128, n0 = bx * 128;
  const int wr = (w >> 1) * 64, wc = (w & 1) * 64;

  const int kpb = K / SPLITK;
  const int kbase = blockIdx.z * kpb;

  f32x4 acc[4][4];
#pragma unroll
  for (int i = 0; i < 4; ++i)
#pragma unroll
    for (int j = 0; j < 4; ++j) acc[i][j] = (f32x4)0.f;

  const int srow = w * 32 + (lane >> 2);
  const int scol = (lane & 3) * 8;
  const u16* gA0 = A + (size_t)(m0 + srow) * K + kbase + scol;
  const u16* gA1 = gA0 + (size_t)16 * K;
  const u16* gB0 = BT + (size_t)(n0 + srow) * K + kbase + scol;
  const u16* gB1 = gB0 + (size_t)16 * K;

  const int arow = lane & 15;
  const int koff = (lane >> 4) * 8;

  auto stage = [&](int buf, int k0) {
    u16* base = smem + buf * 8192;
    gll16(gA0 + k0, base + w * 1024);
    gll16(gA1 + k0, base + w * 1024 + 512);
    gll16(gB0 + k0, base + 4096 + w * 1024);
    gll16(gB1 + k0, base + 4096 + w * 1024 + 512);
  };

  stage(0, 0);

  const int nk = kpb >> 5;
  for (int it = 0; it < nk; ++it) {
    const int buf = it & 1;
    if (it + 1 < nk) {
      stage(buf ^ 1, (it + 1) << 5);   // 4 loads/wave now in flight
      WAIT_VM_BARRIER(4);              // drain only tile-it's loads
    } else {
      WAIT_VM_BARRIER(0);
    }

    const u16* sb = smem + buf * 8192;
    bf16x8 af[4], bff[4];
#pragma unroll
    for (int m = 0; m < 4; ++m)
      af[m] = *(const bf16x8*)&sb[(wr + m * 16 + arow) * 32 + koff];
#pragma unroll
    for (int n = 0; n < 4; ++n)
      bff[n] = *(const bf16x8*)&sb[4096 + (wc + n * 16 + arow) * 32 + koff];
#pragma unroll
    for (int m = 0; m < 4; ++m)
#pragma unroll
      for (int n = 0; n < 4; ++n)
        acc[m][n] = __builtin_amdgcn_mfma_f32_16x16x32_bf16(
            af[m], bff[n], acc[m][n], 0, 0, 0);
    LGKM_BARRIER();  // own ds_reads done; buf may be overwritten next iter
  }

  // epilogue: D layout col=lane&15, row=(lane>>4)*4+reg  [m89-verified]
  u16* Cb = (u16*)C;
  if (SPLITK > 1) Cb += (size_t)blockIdx.z * M * N;
  const int rbase = (lane >> 4) * 4;
  const int cl = lane & 15;
#pragma unroll
  for (int n = 0; n < 4; ++n) {
    const int col = n0 + wc + n * 16 + cl;
    const float bia = BIAS ? bias[col] : 0.f;
#pragma unroll
    for (int m = 0; m < 4; ++m) {
      const int row0 = m0 + wr + m * 16 + rbase;
#pragma unroll
      for (int r = 0; r < 4; ++r) {
        float vv = acc[m][n][r] * scale + bia;
        if (RELU) vv = fmaxf(vv, 0.f);
        const int row = row0 + r;
        if (OUTMODE == 1) {
          Cb[(size_t)row * N + col] = f2bf(vv);
        } else {
          const int reg = col >> 10, cl2 = col & 1023;
          const size_t off =
              (size_t)reg * 4194304 +
              ((size_t)((row >> 11) * NHEAD + (cl2 >> 6)) * T_SEQ +
               (row & 2047)) * 64 + (cl2 & 63);
          Cb[off] = f2bf(vv);
        }
      }
    }
  }
}

// ---------------------------------------------------------------------------
// MFMA causal flash attention, swapped-operand, QBLK=64, 2 waves/block,
// counted-vmcnt pipeline. q,k: [B,H,T,64] bf16 (q pre-scaled by
// 0.125*log2e). vT: [B,H,64,T] bf16. ctx out: [B,T,H,64] bf16.
// Grid: (T/64, B*H), 128 thr; wave = 32 q rows.
// QK^T = mfma(K, Q) -> S^T[s][q]; PV = mfma(V^T, P^T) -> O^T[d][q].
// ---------------------------------------------------------------------------
__global__ __launch_bounds__(128) void attn_mfma(
    const u16* __restrict__ qg, const u16* __restrict__ kg,
    const u16* __restrict__ vtg, u16* __restrict__ ctx) {
  __shared__ u16 Ks[2][64 * 64];
  __shared__ u16 Vs[2][64 * 64];

  const int tid = threadIdx.x;
  const int w = tid >> 6, lane = tid & 63;
  const int qt = gridDim.x - 1 - blockIdx.x;  // big blocks first
  const int bh = blockIdx.y;
  const int l31 = lane & 31, hi32 = lane >> 5;
  const int r8 = lane >> 3, cswz = (lane & 7) ^ r8;

  const u16* qhead = qg + (size_t)bh * (T_SEQ * 64);
  const u16* khead = kg + (size_t)bh * (T_SEQ * 64);
  const u16* vhead = vtg + (size_t)bh * (64 * T_SEQ);

  const int qbase = qt * 64;
  const int qrow = qbase + w * 32 + l31;  // this lane's q row (global t)

  // Q B-fragments (col=l31, k = ks2*16 + hi32*8 + i), resident all kernel
  bf16x8 qb[4];
#pragma unroll
  for (int ks2 = 0; ks2 < 4; ++ks2)
    qb[ks2] = *(const bf16x8*)&qhead[(size_t)qrow * 64 + ks2 * 16 + hi32 * 8];

  f32x16 o0 = (f32x16)0.f, o1 = (f32x16)0.f;  // O^T: d = dv*32 + rowmap
  float m = -INFINITY, l = 0.f;

  const int nt = qt + 1;

  // each of 2 waves stages 32 K rows + 32 V^T rows per tile (8 gll16)
  auto stage = [&](int buf, int s0) {
#pragma unroll
    for (int i = 0; i < 4; ++i) {
      const int row = w * 32 + i * 8 + r8;
      gll16(khead + (size_t)(s0 + row) * 64 + cswz * 8,
            &Ks[buf][(w * 32 + i * 8) * 64]);
      gll16(vhead + (size_t)row * T_SEQ + s0 + cswz * 8,
            &Vs[buf][(w * 32 + i * 8) * 64]);
    }
  };

  stage(0, 0);

  for (int it = 0; it < nt; ++it) {
    const int buf = it & 1;
    if (it + 1 < nt) {
      stage(buf ^ 1, (it + 1) * 64);   // 8 loads/wave now in flight
      WAIT_VM_BARRIER(8);              // drain only tile-it's loads
    } else {
      WAIT_VM_BARRIER(0);
    }

    // ---- QK^T: S^T[s=sub*32+rowmap][q=l31], 8 MFMA 32x32x16
    f32x16 st0 = (f32x16)0.f, st1 = (f32x16)0.f;
    __builtin_amdgcn_s_setprio(1);
#pragma unroll
    for (int ks2 = 0; ks2 < 4; ++ks2) {
      const bf16x8 kf0 = lds_frag(Ks[buf], l31, ks2 * 2 + hi32);
      st0 = __builtin_amdgcn_mfma_f32_32x32x16_bf16(kf0, qb[ks2], st0, 0, 0, 0);
    }
#pragma unroll
    for (int ks2 = 0; ks2 < 4; ++ks2) {
      const bf16x8 kf1 = lds_frag(Ks[buf], 32 + l31, ks2 * 2 + hi32);
      st1 = __builtin_amdgcn_mfma_f32_32x32x16_bf16(kf1, qb[ks2], st1, 0, 0, 0);
    }
    __builtin_amdgcn_s_setprio(0);

    // ---- causal mask (diagonal = last tile)
    if (it == nt - 1) {
      const int s0g = it * 64;
#pragma unroll
      for (int r = 0; r < 16; ++r) {
        const int rowm = (r & 3) + 8 * (r >> 2) + 4 * hi32;
        if (s0g + rowm > qrow) st0[r] = -1e30f;
        if (s0g + 32 + rowm > qrow) st1[r] = -1e30f;
      }
    }

    // ---- online softmax (exp2 domain): s-axis lane-local + 1 swap
    float mx = fmaxf(st0[0], st1[0]);
#pragma unroll
    for (int r = 1; r < 16; ++r) mx = fmaxf(mx, fmaxf(st0[r], st1[r]));
    mx = fmaxf(mx, __shfl_xor(mx, 32));

    float corr = 1.f;
    if (!__all(mx <= m + 11.5f)) {  // defer-max (T13)
      const float mn = fmaxf(m, mx);
      corr = exp2f(m - mn);
      m = mn;
#pragma unroll
      for (int r = 0; r < 16; ++r) { o0[r] *= corr; o1[r] *= corr; }
    }
    float ps = 0.f;
#pragma unroll
    for (int r = 0; r < 16; ++r) {
      st0[r] = exp2f(st0[r] - m);
      st1[r] = exp2f(st1[r] - m);
      ps += st0[r] + st1[r];
    }
    ps += __shfl_xor(ps, 32);
    l = l * corr + ps;

    // ---- P^T B-fragments in-register: cvt_pk + permlane32_swap (T12)
    BF8 pb[4];
#pragma unroll
    for (int blk = 0; blk < 2; ++blk) {
      {
        u32 x0 = cvtpk(st0[blk * 8 + 0], st0[blk * 8 + 1]);
        u32 x1 = cvtpk(st0[blk * 8 + 2], st0[blk * 8 + 3]);
        u32 y0 = cvtpk(st0[blk * 8 + 4], st0[blk * 8 + 5]);
        u32 y1 = cvtpk(st0[blk * 8 + 6], st0[blk * 8 + 7]);
        asm("v_permlane32_swap_b32 %0, %1" : "+v"(x0), "+v"(y0));
        asm("v_permlane32_swap_b32 %0, %1" : "+v"(x1), "+v"(y1));
        pb[blk].u[0] = x0; pb[blk].u[1] = x1;
        pb[blk].u[2] = y0; pb[blk].u[3] = y1;
      }
      {
        u32 x0 = cvtpk(st1[blk * 8 + 0], st1[blk * 8 + 1]);
        u32 x1 = cvtpk(st1[blk * 8 + 2], st1[blk * 8 + 3]);
        u32 y0 = cvtpk(st1[blk * 8 + 4], st1[blk * 8 + 5]);
        u32 y1 = cvtpk(st1[blk * 8 + 6], st1[blk * 8 + 7]);
        asm("v_permlane32_swap_b32 %0, %1" : "+v"(x0), "+v"(y0));
        asm("v_permlane32_swap_b32 %0, %1" : "+v"(x1), "+v"(y1));
        pb[2 + blk].u[0] = x0; pb[2 + blk].u[1] = x1;
        pb[2 + blk].u[2] = y0; pb[2 + blk].u[3] = y1;
      }
    }

    // ---- PV: O^T[d][q] += V^T[d][s] * P^T[s][q], 8 MFMA
    __builtin_amdgcn_s_setprio(1);
#pragma unroll
    for (int ks = 0; ks < 4; ++ks) {
      const bf16x8 vf0 = lds_frag(Vs[buf], l31, ks * 2 + hi32);
      o0 = __builtin_amdgcn_mfma_f32_32x32x16_bf16(vf0, pb[ks].v, o0, 0, 0, 0);
    }
#pragma unroll
    for (int ks = 0; ks < 4; ++ks) {
      const bf16x8 vf1 = lds_frag(Vs[buf], 32 + l31, ks * 2 + hi32);
      o1 = __builtin_amdgcn_mfma_f32_32x32x16_bf16(vf1, pb[ks].v, o1, 0, 0, 0);
    }
    __builtin_amdgcn_s_setprio(0);
    LGKM_BARRIER();  // own ds_reads done; buf may be overwritten next iter
  }

  // ---- epilogue: normalize, transpose O^T->O via per-wave LDS, store ctx
  const float inv = 1.0f / l;
#pragma unroll
  for (int r = 0; r < 16; ++r) { o0[r] *= inv; o1[r] *= inv; }

  u16* ep = &Ks[0][0] + w * 2048;  // per-wave 32q x 64d bf16, chunk-swizzled
#pragma unroll
  for (int rg = 0; rg < 4; ++rg) {
    const u32 w0 = cvtpk(o0[rg * 4 + 0], o0[rg * 4 + 1]);
    const u32 w1 = cvtpk(o0[rg * 4 + 2], o0[rg * 4 + 3]);
    uint2 val; val.x = w0; val.y = w1;
    *(uint2*)&ep[l31 * 64 + ((rg ^ (l31 & 7)) * 8) + hi32 * 4] = val;
  }
#pragma unroll
  for (int rg = 0; rg < 4; ++rg) {
    const u32 w0 = cvtpk(o1[rg * 4 + 0], o1[rg * 4 + 1]);
    const u32 w1 = cvtpk(o1[rg * 4 + 2], o1[rg * 4 + 3]);
    const int chunk = 4 + rg;
    uint2 val; val.x = w0; val.y = w1;
    *(uint2*)&ep[l31 * 64 + ((chunk ^ (l31 & 7)) * 8) + hi32 * 4] = val;
  }

  const int b = bh >> 4, h = bh & 15;
  const int ql = lane >> 1, half = lane & 1;
  const int t = qbase + w * 32 + ql;
  u16* dst = ctx + ((size_t)(b * T_SEQ + t) * NHEAD + h) * 64;
#pragma unroll
  for (int j = 0; j < 4; ++j) {
    const int chunk = half * 4 + j;
    const uint4 vv = *(const uint4*)&ep[ql * 64 + ((chunk ^ (ql & 7)) * 8)];
    *(uint4*)&dst[chunk * 8] = vv;
  }
}

// ---------------------------------------------------------------------------
// out = LayerNorm(x + y0 [+ y1] [+ bias]) * g + be over last dim 1024.
// y0,y1 bf16 (y1 nullable), bias fp32 nullable (per-column).
// ---------------------------------------------------------------------------
template <bool EMIT_BF>
__global__ __launch_bounds__(256) void add_layernorm(
    const float* __restrict__ x, const u16* __restrict__ y0,
    const u16* __restrict__ y1, const float* __restrict__ bias,
    const float* __restrict__ g, const float* __restrict__ be,
    float* __restrict__ out, u16* __restrict__ out_bf) {
  const int row = blockIdx.x;
  const int tid = threadIdx.x;
  const size_t base = (size_t)row * D_MODEL + tid * 4;

  const float4 xv = *(const float4*)&x[base];
  const ushort4 y0v = *(const ushort4*)&y0[base];
  float v0 = xv.x + bf2f(y0v.x), v1 = xv.y + bf2f(y0v.y);
  float v2 = xv.z + bf2f(y0v.z), v3 = xv.w + bf2f(y0v.w);
  if (y1) {
    const ushort4 y1v = *(const ushort4*)&y1[base];
    v0 += bf2f(y1v.x); v1 += bf2f(y1v.y);
    v2 += bf2f(y1v.z); v3 += bf2f(y1v.w);
  }
  if (bias) {
    const float4 bv = *(const float4*)&bias[tid * 4];
    v0 += bv.x; v1 += bv.y; v2 += bv.z; v3 += bv.w;
  }

  float s = v0 + v1 + v2 + v3;
  float ss = v0 * v0 + v1 * v1 + v2 * v2 + v3 * v3;
#pragma unroll
  for (int off = 32; off > 0; off >>= 1) {
    s += __shfl_down(s, off);
    ss += __shfl_down(ss, off);
  }
  __shared__ float red[8];
  const int wid = tid >> 6, lane = tid & 63;
  if (lane == 0) { red[wid] = s; red[4 + wid] = ss; }
  __syncthreads();
  s = red[0] + red[1] + red[2] + red[3];
  ss = red[4] + red[5] + red[6] + red[7];

  const float mean = s * (1.0f / D_MODEL);
  const float var = ss * (1.0f / D_MODEL) - mean * mean;
  const float rr = rsqrtf(var + LN_EPS);

  const float4 g4 = *(const float4*)&g[tid * 4];
  const float4 b4 = *(const float4*)&be[tid * 4];
  float4 o4;
  o4.x = (v0 - mean) * rr * g4.x + b4.x;
  o4.y = (v1 - mean) * rr * g4.y + b4.y;
  o4.z = (v2 - mean) * rr * g4.z + b4.z;
  o4.w = (v3 - mean) * rr * g4.w + b4.w;
  *(float4*)&out[base] = o4;
  if (EMIT_BF) {
    ushort4 ob;
    ob.x = f2bf(o4.x); ob.y = f2bf(o4.y); ob.z = f2bf(o4.z); ob.w = f2bf(o4.w);
    *(ushort4*)&out_bf[base] = ob;
  }
}

// ---------------------------------------------------------------------------
extern "C" void kernel_launch(void* const* d_in, const int* in_sizes, int n_in,
                              void* d_out, int out_size, void* d_ws,
                              size_t ws_size, hipStream_t stream) {
  const float* x  = (const float*)d_in[0];
  const float* Wq = (const float*)d_in[1];
  const float* Wk = (const float*)d_in[2];
  const float* Wv = (const float*)d_in[3];
  const float* Wo = (const float*)d_in[4];
  const float* W1 = (const float*)d_in[5];
  const float* b1 = (const float*)d_in[6];
  const float* W2 = (const float*)d_in[7];
  const float* b2 = (const float*)d_in[8];
  const float* g1 = (const float*)d_in[9];
  const float* be1 = (const float*)d_in[10];
  const float* g2 = (const float*)d_in[11];
  const float* be2 = (const float*)d_in[12];

  char* ws = (char*)d_ws;
  const size_t MB = 1u << 20;
  u16*   x_bf    = (u16*)(ws + 0 * MB);     // 8MB [4096][1024]
  u16*   WqkvT   = (u16*)(ws + 8 * MB);     // 6MB [3072][1024]
  u16*   WoB     = (u16*)(ws + 14 * MB);    // 2MB [1024][1024] (n,k)
  u16*   W1T     = (u16*)(ws + 16 * MB);    // 8MB [4096][1024]
  u16*   W2T     = (u16*)(ws + 24 * MB);    // 8MB [1024][4096]
  u16*   q_bf    = (u16*)(ws + 32 * MB);    // 8MB [B,H,T,64] (qkv contiguous)
  u16*   v_bf    = (u16*)(ws + 48 * MB);    // 8MB [B,H,T,64]
  u16*   vT_bf   = (u16*)(ws + 56 * MB);    // 8MB [B,H,64,T]
  u16*   ctx_bf  = (u16*)(ws + 64 * MB);    // 8MB [B,T,H,64]
  u16*   attn01  = (u16*)(ws + 32 * MB);    // 16MB: Wo split-K halves (q/k dead)
  float* h       = (float*)(ws + 80 * MB);  // 16MB fp32
  u16*   h_bf    = (u16*)(ws + 0 * MB);     // reuse x_bf (dead after QKV)
  u16*   ffn1_bf = (u16*)(ws + 32 * MB);    // 32MB reuse attn01/v/vT after LN1
  u16*   ffn2_01 = (u16*)(ws + 64 * MB);    // 16MB: FFN2 split halves (ctx dead)

  const dim3 blk(256);
  const float lg2e = 1.44269504f;

  conv_f2b<<<NTOK, blk, 0, stream>>>(x, x_bf, NTOK * D_MODEL);
  // fold 1/sqrt(dk) * log2(e) into Wq so QK scores land in exp2 domain
  transpose_f2b<<<dim3(16, 16), blk, 0, stream>>>(Wq, WqkvT, D_MODEL, D_MODEL,
                                                  0.125f * lg2e);
  transpose_f2b<<<dim3(16, 16), blk, 0, stream>>>(Wk, WqkvT + 1024 * 1024,
                                                  D_MODEL, D_MODEL, 1.f);
  transpose_f2b<<<dim3(16, 16), blk, 0, stream>>>(Wv, WqkvT + 2 * 1024 * 1024,
                                                  D_MODEL, D_MODEL, 1.f);
  conv_f2b<<<1024, blk, 0, stream>>>(Wo, WoB, D_MODEL * D_MODEL);
  transpose_f2b<<<dim3(64, 16), blk, 0, stream>>>(W1, W1T, D_MODEL, FF_DIM, 1.f);
  transpose_f2b<<<dim3(16, 64), blk, 0, stream>>>(W2, W2T, FF_DIM, D_MODEL, 1.f);

  // merged QKV projection: [4096,1024] x [3072,1024]^T -> scatter q/k/v
  gemm_mfma<2, false, false, 1><<<dim3(24, 32), blk, 0, stream>>>(
      x_bf, WqkvT, nullptr, q_bf, NTOK, 3072, D_MODEL, 1.f);

  transpose_v<<<dim3(32, 32), blk, 0, stream>>>(v_bf, vT_bf);

  attn_mfma<<<dim3(T_SEQ / 64, 32), dim3(128), 0, stream>>>(
      q_bf, q_bf + 4194304, vT_bf, ctx_bf);

  // output projection, split-K=2 -> two bf16 halves summed in LN1
  gemm_mfma<1, false, false, 2><<<dim3(8, 32, 2), blk, 0, stream>>>(
      ctx_bf, WoB, nullptr, attn01, NTOK, D_MODEL, D_MODEL, 1.f);

  add_layernorm<true><<<NTOK, blk, 0, stream>>>(
      x, attn01, attn01 + 4194304, nullptr, g1, be1, h, h_bf);

  gemm_mfma<1, true, true, 1><<<dim3(32, 32), blk, 0, stream>>>(
      h_bf, W1T, b1, ffn1_bf, NTOK, FF_DIM, D_MODEL, 1.f);

  // FFN2, split-K=2 -> two bf16 halves; b2 folded into LN2
  gemm_mfma<1, false, false, 2><<<dim3(8, 32, 2), blk, 0, stream>>>(
      ffn1_bf, W2T, nullptr, ffn2_01, NTOK, D_MODEL, FF_DIM, 1.f);

  add_layernorm<false><<<NTOK, blk, 0, stream>>>(
      h, ffn2_01, ffn2_01 + 4194304, b2, g2, be2, (float*)d_out, nullptr);
}